// Round 2
// baseline (169.669 us; speedup 1.0000x reference)
//
#include <hip/hip_runtime.h>
#include <hip/hip_bf16.h>
#include <stdint.h>

#define BATCH 8192
#define NSTATE 30
#define DIN 13
#define E1 256
#define E2 128

typedef short bf16x8 __attribute__((ext_vector_type(8)));
typedef float f32x4 __attribute__((ext_vector_type(4)));
typedef __bf16 bf16x2_t __attribute__((ext_vector_type(2)));

// f32 -> bf16 bits, round-to-nearest-even (native cast; compiler emits
// v_cvt_pk_bf16_f32 for pairs -- bit-identical to the old manual RNE)
__device__ __forceinline__ unsigned short f2b(float f) {
    return __builtin_bit_cast(unsigned short, (__bf16)f);
}
__device__ __forceinline__ float b2f(unsigned short b) {
    return __uint_as_float((unsigned)b << 16);
}
__device__ __forceinline__ unsigned pack2(float a, float b) {     // relu+pack
    bf16x2_t v = {(__bf16)fmaxf(a, 0.f), (__bf16)fmaxf(b, 0.f)};
    return __builtin_bit_cast(unsigned, v);
}
__device__ __forceinline__ unsigned pack2n(float a, float b) {    // pack only
    bf16x2_t v = {(__bf16)a, (__bf16)b};
    return __builtin_bit_cast(unsigned, v);
}

// opaque pin: value becomes asm-defined -> cannot be rematerialized from LDS,
// must stay resident in VGPRs (register cache enforcement)
__device__ __forceinline__ bf16x8 pin_frag(bf16x8 v) {
    uint4 u = __builtin_bit_cast(uint4, v);
    asm volatile("" : "+v"(u.x), "+v"(u.y), "+v"(u.z), "+v"(u.w));
    return __builtin_bit_cast(bf16x8, u);
}
__device__ __forceinline__ f32x4 pin_f4(f32x4 v) {
    uint4 u = __builtin_bit_cast(uint4, v);
    asm volatile("" : "+v"(u.x), "+v"(u.y), "+v"(u.z), "+v"(u.w));
    return __builtin_bit_cast(f32x4, u);
}

// combined conv1 weight values (derived R1, verified)
__device__ __forceinline__ float wcat_val(int k, int m, const float* relW, const float* rootW) {
    int part = k >> 7, c = k & 127, grp = m >> 5, mm = m & 31;
    int off = c * 32 + mm;
    if (part == 0) return (grp == 0) ? rootW[4096 + off] + rootW[8192 + off]
                        : (grp == 1) ? relW[off] : relW[3*4096 + off];
    if (part == 1) return (grp == 0) ? relW[1*4096 + off]
                        : (grp == 1) ? relW[6*4096 + off] : relW[5*4096 + off];
    return (grp == 0) ? relW[2*4096 + off]
         : (grp == 1) ? relW[4*4096 + off] : relW[7*4096 + off];
}
__device__ __forceinline__ float wc2_val(int k, int n, const float* relW, const float* rootW) {
    int grp = k >> 5, kk = k & 31;
    int off = kk * 128 + n;
    if (grp == 0) return rootW[4096 + off] + rootW[8192 + off];
    if (grp == 1) return relW[4096 + off];
    return relW[8192 + off];
}

// ---------------------------------------------------------------------------
// k_prep: bias vectors + ALL bf16 MFMA fragment tables (verified decode):
//   entry i -> j=i&7, l=(i>>3)&63, k = ks*32+(l>>4)*8+j, n = nt*16+(l&15)
// R12: W0b tables now carry b0 in A-slot j==INDIM (bias-in-MFMA trick).
// ---------------------------------------------------------------------------
__global__ void k_prep(const float* __restrict__ c1_relW, const float* __restrict__ c1_relb,
                       const float* __restrict__ c1_rootW,
                       const float* __restrict__ c2_relW, const float* __restrict__ c2_relb,
                       const float* __restrict__ c2_rootW,
                       const float* __restrict__ wh_W0, const float* __restrict__ wh_W1,
                       const float* __restrict__ wo_W0, const float* __restrict__ wo_W1,
                       const float* __restrict__ wr_W0, const float* __restrict__ wr_W1,
                       const float* __restrict__ v_W0, const float* __restrict__ v_W1,
                       const float* __restrict__ b0h, const float* __restrict__ b0o,
                       const float* __restrict__ b0r,
                       float* __restrict__ bcat, float* __restrict__ bc2,
                       unsigned short* __restrict__ W0b_h, unsigned short* __restrict__ W0b_o,
                       unsigned short* __restrict__ W0b_r,
                       unsigned short* __restrict__ W1f_h, unsigned short* __restrict__ W1f_o,
                       unsigned short* __restrict__ W1f_r,
                       unsigned short* __restrict__ Mf_h, unsigned short* __restrict__ Mf_o,
                       unsigned short* __restrict__ Wcatf, unsigned short* __restrict__ Wc2f,
                       unsigned short* __restrict__ vW0f, unsigned short* __restrict__ vW1f)
{
    int gid = blockIdx.x * blockDim.x + threadIdx.x;
    int gsz = gridDim.x * blockDim.x;

    for (int i = gid; i < 96; i += gsz) {
        int grp = i >> 5, mm = i & 31;
        float v;
        if (grp == 0)      v = c1_relb[32 + mm] + c1_relb[64 + mm];
        else if (grp == 1) v = c1_relb[mm] + c1_relb[128 + mm] + c1_relb[192 + mm];
        else               v = c1_relb[96 + mm] + c1_relb[160 + mm] + c1_relb[224 + mm];
        bcat[i] = v;
    }
    for (int i = gid; i < 128; i += gsz) bc2[i] = c2_relb[128 + i] + c2_relb[256 + i];

    for (int i = gid; i < 2048; i += gsz) {
        int n = i >> 3, j = i & 7;
        W0b_h[i] = (j < 7) ? f2b(wh_W0[j * 256 + n]) : f2b(b0h[n]);
        W0b_o[i] = (j < 7) ? f2b(wo_W0[j * 256 + n]) : f2b(b0o[n]);
        W0b_r[i] = (j < 6) ? f2b(wr_W0[j * 256 + n])
                 : (j == 6) ? f2b(b0r[n]) : (unsigned short)0;
    }
    for (int i = gid; i < 32768; i += gsz) {
        int j = i & 7, l = (i >> 3) & 63, nt = (i >> 9) & 7, ks = i >> 12;
        int k = ks * 32 + (l >> 4) * 8 + j;
        int n = nt * 16 + (l & 15);
        W1f_h[i] = f2b(wh_W1[k * 128 + n]);
        W1f_o[i] = f2b(wo_W1[k * 128 + n]);
        W1f_r[i] = f2b(wr_W1[k * 128 + n]);
    }
    for (int i = gid; i < 4096; i += gsz) {
        int j = i & 7, l = (i >> 3) & 63, nt = (i >> 9) & 1, ks = i >> 10;
        int k = ks * 32 + (l >> 4) * 8 + j;
        int n = nt * 16 + (l & 15);
        int i0 = k * 32 + n;
        Mf_h[i] = f2b(c1_rootW[i0] + c1_rootW[4*4096 + i0] + c1_rootW[6*4096 + i0] - c1_relW[6*4096 + i0]);
        Mf_o[i] = f2b(c1_rootW[3*4096 + i0] + c1_rootW[5*4096 + i0] + c1_rootW[7*4096 + i0] - c1_relW[7*4096 + i0]);
    }
    for (int i = gid; i < 36864; i += gsz) {
        int j = i & 7, l = (i >> 3) & 63, rem = i >> 9;
        int nt = rem % 6, ks = rem / 6;
        int k = ks * 32 + (l >> 4) * 8 + j;
        int n = nt * 16 + (l & 15);
        Wcatf[i] = f2b(wcat_val(k, n, c1_relW, c1_rootW));
    }
    for (int i = gid; i < 12288; i += gsz) {
        int j = i & 7, l = (i >> 3) & 63, rem = i >> 9;
        int nt = rem & 7, ks = rem >> 3;
        int k = ks * 32 + (l >> 4) * 8 + j;
        int n = nt * 16 + (l & 15);
        Wc2f[i] = f2b(wc2_val(k, n, c2_relW, c2_rootW));
    }
    for (int i = gid; i < 32768; i += gsz) {
        int j = i & 7, l = (i >> 3) & 63, rem = i >> 9;
        int nt = rem & 15, ks = rem >> 4;
        int k = ks * 32 + (l >> 4) * 8 + j;
        int n = nt * 16 + (l & 15);
        vW0f[i] = f2b(v_W0[k * 256 + n]);
    }
    for (int i = gid; i < 32768; i += gsz) {
        int j = i & 7, l = (i >> 3) & 63, rem = i >> 9;
        int nt = rem & 7, ks = rem >> 3;
        int k = ks * 32 + (l >> 4) * 8 + j;
        int n = nt * 16 + (l & 15);
        vW1f[i] = f2b(v_W1[k * 128 + n]);
    }
}

// ---------------------------------------------------------------------------
// mlp_blockE: R9/R10-verified barrier-free per-wave pipeline.
// R12 changes: (a) W1 A-fragments nt=0..3 FORCE-cached via opaque-asm pin
// (128 VGPR; R11's un-pinned version was rematerialized by the allocator);
// (b) layer-1 bias folded into MFMA A-slot j=INDIM with bx[INDIM]=1.0 —
// no b0s LDS reads at all; (c) layer-2 bias hoisted to 32 pinned VGPRs.
// Per-sub LDS traffic 128KB -> ~72KB.
// LDS: W0s@0 4K | Mfs@4K 8K | W1s@12K 64K | (b0s dead) | b1s@78848 0.5K |
//      hs@79360 8x8448 = 143.5K total.
// ---------------------------------------------------------------------------
#define SM_W0   0
#define SM_MF   4096
#define SM_W1   12288
#define SM_B1   78848
#define SM_HS   79360
#define SM_SZ   (79360 + 8 * 16 * 264 * 2)

template<int NPB, int NODE0, int INOFF, int INDIM, bool TAIL>
__device__ __forceinline__ void mlp_blockE(
    int blkrow0, const float* __restrict__ state,
    const unsigned short* __restrict__ W0b_g,
    const unsigned short* __restrict__ W1f_g, const float* __restrict__ b1,
    const unsigned short* __restrict__ Mf_g,
    unsigned short* __restrict__ tR, float* __restrict__ sumB,
    unsigned short* __restrict__ eR, char* smem)
{
    unsigned short* W0s = (unsigned short*)(smem + SM_W0);
    unsigned short* Mfs = (unsigned short*)(smem + SM_MF);
    unsigned short* W1s = (unsigned short*)(smem + SM_W1);
    float* b1s          = (float*)(smem + SM_B1);

    const int t = threadIdx.x;
    const int lane = t & 63;
    const int w = t >> 6;
    const int l15 = lane & 15;
    const int quad = lane >> 4;
    const int R0 = blkrow0 + w * 128;     // this wave's 128 contiguous rows
    unsigned short* hw = (unsigned short*)(smem + SM_HS) + w * (16 * 264); // [16][264]
    unsigned short* ew = hw;                                              // alias [16][136]

    // ---- one-time staging ----
    if (t < 256) ((uint4*)W0s)[t] = ((const uint4*)W0b_g)[t];
    if (t >= 256 && t < 384) b1s[t - 256] = b1[t - 256];
    #pragma unroll
    for (int i = 0; i < 8; ++i)
        ((uint4*)W1s)[t + 512 * i] = ((const uint4*)W1f_g)[t + 512 * i];
    if constexpr (TAIL)
        ((uint4*)Mfs)[t] = ((const uint4*)Mf_g)[t];
    __syncthreads();   // the ONLY block-wide barrier

    // ---- W1 fragment register cache: nt=0..3, all ks (32 frags = 128 VGPR),
    // pinned so the allocator cannot rematerialize the ds_reads per sub.
    // LDS caps occupancy at 1 block/CU (2 waves/SIMD) so <=256 VGPRs is free.
    bf16x8 wreg[32];
    #pragma unroll
    for (int ks = 0; ks < 8; ++ks)
        #pragma unroll
        for (int nt = 0; nt < 4; ++nt)
            wreg[ks * 4 + nt] =
                pin_frag(*(const bf16x8*)(W1s + ((ks * 8 + nt) * 64 + lane) * 8));

    // ---- layer-2 bias in registers (32 VGPR, pinned) ----
    f32x4 bias1[8];
    #pragma unroll
    for (int nt = 0; nt < 8; ++nt) {
        float4 bb = *(const float4*)(b1s + nt * 16 + quad * 4);
        bias1[nt] = pin_f4((f32x4){bb.x, bb.y, bb.z, bb.w});
    }

    float s0 = 0.f, s1 = 0.f;
    int bcur = R0 / NPB;

    // ---- X pipeline: load floats for sub 0 now; each sub prefetches sub+1 ----
    float xf[INDIM];
    #pragma unroll 1
    for (int dummy = 0; dummy < 1; ++dummy) {
        if (quad == 0) {
            int grow = R0 + l15;
            int b = grow / NPB;
            int n = grow - b * NPB + NODE0;
            const float* xp = state + ((size_t)b * NSTATE + n) * DIN + INOFF;
            #pragma unroll
            for (int j = 0; j < INDIM; ++j) xf[j] = xp[j];
        }
    }

    for (int sub = 0; sub < 8; ++sub) {
        const int wrow0 = R0 + sub * 16;

        // ---- X: convert current (bias slot k=INDIM gets 1.0), then issue
        // next sub's loads (latency hides under layer2 + tail) ----
        bf16x8 bx = {};
        if (quad == 0) {
            #pragma unroll
            for (int j = 0; j < INDIM; ++j)
                bx[j] = (short)f2b(xf[j]);
            bx[INDIM] = (short)0x3F80;   // 1.0bf16 multiplies the b0 A-slot
        }
        if (sub < 7 && quad == 0) {
            int grow = wrow0 + 16 + l15;
            int b = grow / NPB;
            int n = grow - b * NPB + NODE0;
            const float* xp = state + ((size_t)b * NSTATE + n) * DIN + INOFF;
            #pragma unroll
            for (int j = 0; j < INDIM; ++j) xf[j] = xp[j];
        }

        // ---- layer 1 (swapped): lane holds h[r=l15][n=nt*16+quad*4+reg];
        // bias comes through the MFMA (A-slot j=INDIM), acc starts at 0 ----
        #pragma unroll
        for (int nt = 0; nt < 16; ++nt) {
            bf16x8 aw = {};
            if (quad == 0)
                aw = *(const bf16x8*)(W0s + (nt * 16 + l15) * 8);
            f32x4 c = {0.f, 0.f, 0.f, 0.f};
            c = __builtin_amdgcn_mfma_f32_16x16x32_bf16(aw, bx, c, 0, 0, 0);
            uint2 pv = {pack2(c[0], c[1]), pack2(c[2], c[3])};
            *(uint2*)(hw + l15 * 264 + nt * 16 + quad * 4) = pv;
        }

        // ---- layer 2 (swapped): lane holds e[r=l15][n=nt*16+quad*4+reg] ----
        f32x4 acc[8];
        #pragma unroll
        for (int nt = 0; nt < 8; ++nt) acc[nt] = bias1[nt];
        #pragma unroll
        for (int ks = 0; ks < 8; ++ks) {
            bf16x8 bh = *(const bf16x8*)(hw + l15 * 264 + ks * 32 + quad * 8);
            #pragma unroll
            for (int nt = 0; nt < 8; ++nt) {
                bf16x8 aw = (nt < 4)
                    ? wreg[ks * 4 + nt]
                    : *(const bf16x8*)(W1s + ((ks * 8 + nt) * 64 + lane) * 8);
                acc[nt] = __builtin_amdgcn_mfma_f32_16x16x32_bf16(aw, bh, acc[nt], 0, 0, 0);
            }
        }

        if constexpr (TAIL) {
            // intra-wave WAR: hs reads complete before ew overwrite
            __asm__ __volatile__("s_waitcnt lgkmcnt(0)" ::: "memory");
            #pragma unroll
            for (int nt = 0; nt < 8; ++nt) {
                uint2 pv = {pack2(acc[nt][0], acc[nt][1]), pack2(acc[nt][2], acc[nt][3])};
                *(uint2*)(ew + l15 * 136 + nt * 16 + quad * 4) = pv;
            }

            // t = e @ M, SWAPPED (A=Mf frag, B=e frag) -> D=(e@M)^T:
            // lane holds t[row=wrow0+l15][cols nt*16+quad*4 .. +3]
            f32x4 tacc[2] = {{0.f,0.f,0.f,0.f},{0.f,0.f,0.f,0.f}};
            #pragma unroll
            for (int ks = 0; ks < 4; ++ks) {
                bf16x8 ae = *(const bf16x8*)(ew + l15 * 136 + ks * 32 + quad * 8);
                #pragma unroll
                for (int nt = 0; nt < 2; ++nt) {
                    bf16x8 bm = *(const bf16x8*)(Mfs + ((ks * 2 + nt) * 64 + lane) * 8);
                    tacc[nt] = __builtin_amdgcn_mfma_f32_16x16x32_bf16(bm, ae, tacc[nt], 0, 0, 0);
                }
            }
            #pragma unroll
            for (int nt = 0; nt < 2; ++nt) {
                uint2 pv = {pack2n(tacc[nt][0], tacc[nt][1]), pack2n(tacc[nt][2], tacc[nt][3])};
                *(uint2*)(tR + (size_t)(wrow0 + l15) * 32 + nt * 16 + quad * 4) = pv;
            }

            // per-b sums in registers (cols 2*lane, 2*lane+1); flush at b bounds
            #pragma unroll
            for (int r = 0; r < 16; ++r) {
                int b = (wrow0 + r) / NPB;
                if (b != bcur) {
                    bool interior = (bcur * NPB >= R0) && ((bcur + 1) * NPB <= R0 + 128);
                    float* dst = sumB + (size_t)bcur * 128 + 2 * lane;
                    if (interior) { dst[0] = s0; dst[1] = s1; }
                    else { atomicAdd(dst, s0); atomicAdd(dst + 1, s1); }
                    s0 = 0.f; s1 = 0.f; bcur = b;
                }
                unsigned v = *(const unsigned*)(ew + r * 136 + lane * 2);
                s0 += b2f((unsigned short)v);
                s1 += b2f((unsigned short)(v >> 16));
            }
            if (sub == 7) {
                bool interior = (bcur * NPB >= R0) && ((bcur + 1) * NPB <= R0 + 128);
                float* dst = sumB + (size_t)bcur * 128 + 2 * lane;
                if (interior) { dst[0] = s0; dst[1] = s1; }
                else { atomicAdd(dst, s0); atomicAdd(dst + 1, s1); }
            }
        } else {
            // root: direct row-major global store eR[row][n]
            #pragma unroll
            for (int nt = 0; nt < 8; ++nt) {
                uint2 pv = {pack2(acc[nt][0], acc[nt][1]), pack2(acc[nt][2], acc[nt][3])};
                *(uint2*)(eR + (size_t)(wrow0 + l15) * 128 + nt * 16 + quad * 4) = pv;
            }
        }
        __asm__ __volatile__("" ::: "memory");   // keep iteration LDS order
    }
}

__global__ __launch_bounds__(512, 2) void k_mlpE(
    const float* __restrict__ state,
    const unsigned short* __restrict__ W0b_h,
    const unsigned short* __restrict__ W1f_h, const float* __restrict__ b1_h,
    const unsigned short* __restrict__ Mf_h, unsigned short* __restrict__ tR_h,
    float* __restrict__ shB,
    const unsigned short* __restrict__ W0b_o,
    const unsigned short* __restrict__ W1f_o, const float* __restrict__ b1_o,
    const unsigned short* __restrict__ Mf_o, unsigned short* __restrict__ tR_o,
    float* __restrict__ soB,
    const unsigned short* __restrict__ W0b_r,
    const unsigned short* __restrict__ W1f_r, const float* __restrict__ b1_r,
    unsigned short* __restrict__ eR)
{
    __shared__ __align__(16) char smem[SM_SZ];
    int bid = blockIdx.x;
    if (bid < 160)
        mlp_blockE<20, 0, 6, 7, true>(bid * 1024, state, W0b_h, W1f_h, b1_h,
                                      Mf_h, tR_h, shB, nullptr, smem);
    else if (bid < 240)
        mlp_blockE<10, 20, 6, 7, true>((bid - 160) * 1024, state, W0b_o, W1f_o, b1_o,
                                       Mf_o, tR_o, soB, nullptr, smem);
    else
        mlp_blockE<1, 0, 0, 6, false>((bid - 240) * 1024, state, W0b_r, W1f_r, b1_r,
                                      nullptr, nullptr, nullptr, eR, smem);
}

// ---------------------------------------------------------------------------
// k_tail: FUSED u2 + sM + v, 16 b's per block, 512 blocks (2 blocks/CU,
// two independent barrier groups per CU). M=16 fills the MFMA exactly;
// N-tiles strided across the 4 waves.
// LDS 33KB: Ub[16][400] (V1b aliases) | Vb[16][104] | chL/coL | Hb | V2b
// ---------------------------------------------------------------------------
__global__ __launch_bounds__(256, 2) void k_tail(
    const unsigned short* __restrict__ eR,
    const float* __restrict__ shB, const float* __restrict__ soB,
    const unsigned short* __restrict__ tR_h, const unsigned short* __restrict__ tR_o,
    const unsigned short* __restrict__ Wcatf, const float* __restrict__ bcat,
    const unsigned short* __restrict__ Wc2f, const float* __restrict__ bc2,
    const unsigned short* __restrict__ vW0f, const float* __restrict__ vb0,
    const unsigned short* __restrict__ vW1f, const float* __restrict__ vb1,
    const float* __restrict__ vW2, const float* __restrict__ vb2,
    float* __restrict__ out)
{
    __shared__ __align__(16) char sm[33024];
    unsigned short* Ub  = (unsigned short*)(sm);          // [16][400]
    unsigned short* V1b = (unsigned short*)(sm);          // alias  [16][264]
    unsigned short* Vb  = (unsigned short*)(sm + 12800);  // [16][104]
    float* chL          = (float*)(sm + 16128);           // [16][32]
    float* coL          = (float*)(sm + 18176);           // [16][32]
    unsigned short* Hb  = (unsigned short*)(sm + 20224);  // [16][136]
    float* V2b          = (float*)(sm + 24576);           // [16][132]

    const int t = threadIdx.x, lane = t & 63, w = t >> 6;
    const int l15 = lane & 15, quad = lane >> 4;
    const int b0 = blockIdx.x * 16;
    const int rowb = quad * 4;

    // ---- phase 1: stage U = [er | sh | so] ----
    {
        int b = t >> 4, q = t & 15;
        ((uint4*)(Ub + b * 400))[q] = ((const uint4*)(eR + (size_t)(b0 + b) * 128))[q];
    }
    for (int idx = t; idx < 4096; idx += 256) {
        int b = idx >> 8, kk = idx & 255;
        float v = (kk < 128) ? shB[(size_t)(b0 + b) * 128 + kk]
                             : soB[(size_t)(b0 + b) * 128 + kk - 128];
        Ub[b * 400 + 128 + kk] = f2b(v);
    }
    __syncthreads();

    // ---- phase 2: U-MFMA (unswapped, verified): xr / ch / co ----
    for (int nt = w; nt < 6; nt += 4) {
        float bias = bcat[nt * 16 + l15];
        f32x4 acc = {bias, bias, bias, bias};
        #pragma unroll
        for (int ks = 0; ks < 12; ++ks) {
            bf16x8 a = *(const bf16x8*)(Ub + l15 * 400 + ks * 32 + quad * 8);
            bf16x8 bw = *(const bf16x8*)(Wcatf + ((ks * 6 + nt) * 64 + lane) * 8);
            acc = __builtin_amdgcn_mfma_f32_16x16x32_bf16(a, bw, acc, 0, 0, 0);
        }
        int n = nt * 16 + l15;
        #pragma unroll
        for (int reg = 0; reg < 4; ++reg) {
            float v = acc[reg];
            int b = rowb + reg;
            if (n < 32)      Vb[b * 104 + n] = f2b(fmaxf(v, 0.f));
            else if (n < 64) chL[b * 32 + (n - 32)] = v;
            else             coL[b * 32 + (n - 64)] = v;
        }
    }
    __syncthreads();

    // ---- phase 3: t-scan (row-major tR, coalesced) -> s2h, s2o ----
    for (int idx = t; idx < 512; idx += 256) {
        int b = idx >> 5, m = idx & 31;
        float ch = chL[b * 32 + m];
        const unsigned short* p = tR_h + (size_t)(b0 + b) * 20 * 32 + m;
        float s = 0.f;
        #pragma unroll
        for (int n = 0; n < 20; ++n) s += fmaxf(ch + b2f(p[n * 32]), 0.f);
        Vb[b * 104 + 32 + m] = f2b(s);
        float co = coL[b * 32 + m];
        const unsigned short* p2 = tR_o + (size_t)(b0 + b) * 10 * 32 + m;
        float s2 = 0.f;
        #pragma unroll
        for (int n = 0; n < 10; ++n) s2 += fmaxf(co + b2f(p2[n * 32]), 0.f);
        Vb[b * 104 + 64 + m] = f2b(s2);
    }
    __syncthreads();

    // ---- phase 4: c2 (N=128, 2 nt per wave) ----
    {
        f32x4 acc[2];
        #pragma unroll
        for (int q = 0; q < 2; ++q) {
            int nt = w + q * 4;
            float bias = bc2[nt * 16 + l15];
            acc[q] = (f32x4){bias, bias, bias, bias};
        }
        #pragma unroll
        for (int ks = 0; ks < 3; ++ks) {
            bf16x8 a = *(const bf16x8*)(Vb + l15 * 104 + ks * 32 + quad * 8);
            #pragma unroll
            for (int q = 0; q < 2; ++q) {
                int nt = w + q * 4;
                bf16x8 bw = *(const bf16x8*)(Wc2f + ((ks * 8 + nt) * 64 + lane) * 8);
                acc[q] = __builtin_amdgcn_mfma_f32_16x16x32_bf16(a, bw, acc[q], 0, 0, 0);
            }
        }
        #pragma unroll
        for (int q = 0; q < 2; ++q) {
            int nt = w + q * 4;
            #pragma unroll
            for (int reg = 0; reg < 4; ++reg)
                Hb[(rowb + reg) * 136 + nt * 16 + l15] = f2b(fmaxf(acc[q][reg], 0.f));
        }
    }
    __syncthreads();

    // ---- phase 5: v1 (N=256, 4 nt per wave; V1b aliases dead Ub) ----
    {
        f32x4 acc[4];
        #pragma unroll
        for (int q = 0; q < 4; ++q) {
            int nt = w + q * 4;
            float bias = vb0[nt * 16 + l15];
            acc[q] = (f32x4){bias, bias, bias, bias};
        }
        #pragma unroll
        for (int ks = 0; ks < 4; ++ks) {
            bf16x8 a = *(const bf16x8*)(Hb + l15 * 136 + ks * 32 + quad * 8);
            #pragma unroll
            for (int q = 0; q < 4; ++q) {
                int nt = w + q * 4;
                bf16x8 bw = *(const bf16x8*)(vW0f + ((ks * 16 + nt) * 64 + lane) * 8);
                acc[q] = __builtin_amdgcn_mfma_f32_16x16x32_bf16(a, bw, acc[q], 0, 0, 0);
            }
        }
        __syncthreads();   // Ub reads (phase-2 done long ago) -> safe; order vs writes
        #pragma unroll
        for (int q = 0; q < 4; ++q) {
            int nt = w + q * 4;
            #pragma unroll
            for (int reg = 0; reg < 4; ++reg)
                V1b[(rowb + reg) * 264 + nt * 16 + l15] = f2b(fmaxf(acc[q][reg], 0.f));
        }
    }
    __syncthreads();

    // ---- phase 6: v2 (N=128, 2 nt per wave) ----
    {
        f32x4 acc[2];
        #pragma unroll
        for (int q = 0; q < 2; ++q) {
            int nt = w + q * 4;
            float bias = vb1[nt * 16 + l15];
            acc[q] = (f32x4){bias, bias, bias, bias};
        }
        #pragma unroll
        for (int ks = 0; ks < 8; ++ks) {
            bf16x8 a = *(const bf16x8*)(V1b + l15 * 264 + ks * 32 + quad * 8);
            #pragma unroll
            for (int q = 0; q < 2; ++q) {
                int nt = w + q * 4;
                bf16x8 bw = *(const bf16x8*)(vW1f + ((ks * 8 + nt) * 64 + lane) * 8);
                acc[q] = __builtin_amdgcn_mfma_f32_16x16x32_bf16(a, bw, acc[q], 0, 0, 0);
            }
        }
        #pragma unroll
        for (int q = 0; q < 2; ++q) {
            int nt = w + q * 4;
            #pragma unroll
            for (int reg = 0; reg < 4; ++reg)
                V2b[(rowb + reg) * 132 + nt * 16 + l15] = fmaxf(acc[q][reg], 0.f);
        }
    }
    __syncthreads();

    // ---- phase 7: v3, 8 threads per b + shuffle reduce ----
    if (t < 128) {
        int b = t >> 3, j = t & 7;
        float v = 0.f;
        #pragma unroll
        for (int k = 0; k < 16; ++k)
            v = fmaf(V2b[b * 132 + j * 16 + k], vW2[j * 16 + k], v);
        v += __shfl_down(v, 4, 8);
        v += __shfl_down(v, 2, 8);
        v += __shfl_down(v, 1, 8);
        if (j == 0) out[b0 + b] = v + vb2[0];
    }
}

// ---------------------------------------------------------------------------
extern "C" void kernel_launch(void* const* d_in, const int* in_sizes, int n_in,
                              void* d_out, int out_size, void* d_ws, size_t ws_size,
                              hipStream_t stream)
{
    const float* state   = (const float*)d_in[0];
    const float* wr_W0   = (const float*)d_in[2];
    const float* wr_b0   = (const float*)d_in[3];
    const float* wr_W1   = (const float*)d_in[4];
    const float* wr_b1   = (const float*)d_in[5];
    const float* wh_W0   = (const float*)d_in[6];
    const float* wh_b0   = (const float*)d_in[7];
    const float* wh_W1   = (const float*)d_in[8];
    const float* wh_b1   = (const float*)d_in[9];
    const float* wo_W0   = (const float*)d_in[10];
    const float* wo_b0   = (const float*)d_in[11];
    const float* wo_W1   = (const float*)d_in[12];
    const float* wo_b1   = (const float*)d_in[13];
    const float* c1_relW = (const float*)d_in[14];
    const float* c1_relb = (const float*)d_in[15];
    const float* c1_rootW= (const float*)d_in[16];
    const float* c2_relW = (const float*)d_in[17];
    const float* c2_relb = (const float*)d_in[18];
    const float* c2_rootW= (const float*)d_in[19];
    const float* v_W0    = (const float*)d_in[20];
    const float* v_b0    = (const float*)d_in[21];
    const float* v_W1    = (const float*)d_in[22];
    const float* v_b1    = (const float*)d_in[23];
    const float* v_W2    = (const float*)d_in[24];
    const float* v_b2    = (const float*)d_in[25];

    char* ws = (char*)d_ws;
    size_t off = 0;
    auto alloc = [&](size_t bytes) -> char* {
        char* p = ws + off;
        off = (off + bytes + 255) & ~(size_t)255;
        return p;
    };
    float* shB  = (float*)alloc((size_t)BATCH * 128 * 4);          // b-major sums
    float* soB  = (float*)alloc((size_t)BATCH * 128 * 4);          // contiguous with shB
    unsigned short* tR_h = (unsigned short*)alloc((size_t)163840 * 32 * 2);  // row-major
    unsigned short* tR_o = (unsigned short*)alloc((size_t)81920 * 32 * 2);   // row-major
    unsigned short* eR   = (unsigned short*)alloc((size_t)BATCH * 128 * 2);
    float* bcat = (float*)alloc(96 * 4);
    float* bc2  = (float*)alloc(128 * 4);
    unsigned short* W0b_h = (unsigned short*)alloc(2048 * 2);
    unsigned short* W0b_o = (unsigned short*)alloc(2048 * 2);
    unsigned short* W0b_r = (unsigned short*)alloc(2048 * 2);
    unsigned short* W1f_h = (unsigned short*)alloc(32768 * 2);
    unsigned short* W1f_o = (unsigned short*)alloc(32768 * 2);
    unsigned short* W1f_r = (unsigned short*)alloc(32768 * 2);
    unsigned short* Mf_h  = (unsigned short*)alloc(4096 * 2);
    unsigned short* Mf_o  = (unsigned short*)alloc(4096 * 2);
    unsigned short* Wcatf = (unsigned short*)alloc(36864 * 2);
    unsigned short* Wc2f  = (unsigned short*)alloc(12288 * 2);
    unsigned short* vW0f  = (unsigned short*)alloc(32768 * 2);
    unsigned short* vW1f  = (unsigned short*)alloc(32768 * 2);
    (void)ws_size; (void)in_sizes; (void)n_in; (void)out_size;

    hipMemsetAsync(shB, 0, (size_t)2 * BATCH * 128 * 4, stream);

    k_prep<<<256, 256, 0, stream>>>(c1_relW, c1_relb, c1_rootW, c2_relW, c2_relb, c2_rootW,
                                    wh_W0, wh_W1, wo_W0, wo_W1, wr_W0, wr_W1, v_W0, v_W1,
                                    wh_b0, wo_b0, wr_b0,
                                    bcat, bc2, W0b_h, W0b_o, W0b_r, W1f_h, W1f_o, W1f_r,
                                    Mf_h, Mf_o, Wcatf, Wc2f, vW0f, vW1f);

    k_mlpE<<<248, 512, 0, stream>>>(state,
                                    W0b_h, W1f_h, wh_b1, Mf_h, tR_h, shB,
                                    W0b_o, W1f_o, wo_b1, Mf_o, tR_o, soB,
                                    W0b_r, W1f_r, wr_b1, eR);

    k_tail<<<512, 256, 0, stream>>>(eR, shB, soB, tR_h, tR_o,
                                    Wcatf, bcat, Wc2f, bc2, vW0f, v_b0, vW1f, v_b1,
                                    v_W2, v_b2, (float*)d_out);
}

// Round 3
// 164.568 us; speedup vs baseline: 1.0310x; 1.0310x over previous
//
#include <hip/hip_runtime.h>
#include <hip/hip_bf16.h>
#include <stdint.h>

#define BATCH 8192
#define NSTATE 30
#define DIN 13
#define E1 256
#define E2 128

typedef short bf16x8 __attribute__((ext_vector_type(8)));
typedef float f32x4 __attribute__((ext_vector_type(4)));
typedef __bf16 bf16x2_t __attribute__((ext_vector_type(2)));

// f32 -> bf16 bits, round-to-nearest-even (native cast; compiler emits
// v_cvt_pk_bf16_f32 for pairs -- bit-identical to the old manual RNE)
__device__ __forceinline__ unsigned short f2b(float f) {
    return __builtin_bit_cast(unsigned short, (__bf16)f);
}
__device__ __forceinline__ float b2f(unsigned short b) {
    return __uint_as_float((unsigned)b << 16);
}
__device__ __forceinline__ unsigned pack2(float a, float b) {     // relu+pack
    bf16x2_t v = {(__bf16)fmaxf(a, 0.f), (__bf16)fmaxf(b, 0.f)};
    return __builtin_bit_cast(unsigned, v);
}
__device__ __forceinline__ unsigned pack2n(float a, float b) {    // pack only
    bf16x2_t v = {(__bf16)a, (__bf16)b};
    return __builtin_bit_cast(unsigned, v);
}

__device__ __forceinline__ f32x4 pin_f4(f32x4 v) {
    uint4 u = __builtin_bit_cast(uint4, v);
    asm volatile("" : "+v"(u.x), "+v"(u.y), "+v"(u.z), "+v"(u.w));
    return __builtin_bit_cast(f32x4, u);
}

// combined conv1 weight values (derived R1, verified)
__device__ __forceinline__ float wcat_val(int k, int m, const float* relW, const float* rootW) {
    int part = k >> 7, c = k & 127, grp = m >> 5, mm = m & 31;
    int off = c * 32 + mm;
    if (part == 0) return (grp == 0) ? rootW[4096 + off] + rootW[8192 + off]
                        : (grp == 1) ? relW[off] : relW[3*4096 + off];
    if (part == 1) return (grp == 0) ? relW[1*4096 + off]
                        : (grp == 1) ? relW[6*4096 + off] : relW[5*4096 + off];
    return (grp == 0) ? relW[2*4096 + off]
         : (grp == 1) ? relW[4*4096 + off] : relW[7*4096 + off];
}
__device__ __forceinline__ float wc2_val(int k, int n, const float* relW, const float* rootW) {
    int grp = k >> 5, kk = k & 31;
    int off = kk * 128 + n;
    if (grp == 0) return rootW[4096 + off] + rootW[8192 + off];
    if (grp == 1) return relW[4096 + off];
    return relW[8192 + off];
}

// ---------------------------------------------------------------------------
// k_prep: bias vectors + ALL bf16 MFMA fragment tables (verified decode):
//   entry i -> j=i&7, l=(i>>3)&63, k = ks*32+(l>>4)*8+j, n = nt*16+(l&15)
// R12: W0b carries b0 in A-slot j==INDIM (bias-in-MFMA).
// R13: W1f rows and Mf rows are PERMUTED so layer-2 / t-MFMA B-operands come
// directly from the producing MFMA's accumulator registers (no LDS transpose):
//   W1f row k=ks*32+quad*8+j  <- original E1 row ((j>>2)*8+ks)*16+quad*4+(j&3)
//   Mf  row k=ks*32+quad*8+j  <- original E2 row ((j>>2)*4+ks)*16+quad*4+(j&3)
// ---------------------------------------------------------------------------
__global__ void k_prep(const float* __restrict__ c1_relW, const float* __restrict__ c1_relb,
                       const float* __restrict__ c1_rootW,
                       const float* __restrict__ c2_relW, const float* __restrict__ c2_relb,
                       const float* __restrict__ c2_rootW,
                       const float* __restrict__ wh_W0, const float* __restrict__ wh_W1,
                       const float* __restrict__ wo_W0, const float* __restrict__ wo_W1,
                       const float* __restrict__ wr_W0, const float* __restrict__ wr_W1,
                       const float* __restrict__ v_W0, const float* __restrict__ v_W1,
                       const float* __restrict__ b0h, const float* __restrict__ b0o,
                       const float* __restrict__ b0r,
                       float* __restrict__ bcat, float* __restrict__ bc2,
                       unsigned short* __restrict__ W0b_h, unsigned short* __restrict__ W0b_o,
                       unsigned short* __restrict__ W0b_r,
                       unsigned short* __restrict__ W1f_h, unsigned short* __restrict__ W1f_o,
                       unsigned short* __restrict__ W1f_r,
                       unsigned short* __restrict__ Mf_h, unsigned short* __restrict__ Mf_o,
                       unsigned short* __restrict__ Wcatf, unsigned short* __restrict__ Wc2f,
                       unsigned short* __restrict__ vW0f, unsigned short* __restrict__ vW1f)
{
    int gid = blockIdx.x * blockDim.x + threadIdx.x;
    int gsz = gridDim.x * blockDim.x;

    for (int i = gid; i < 96; i += gsz) {
        int grp = i >> 5, mm = i & 31;
        float v;
        if (grp == 0)      v = c1_relb[32 + mm] + c1_relb[64 + mm];
        else if (grp == 1) v = c1_relb[mm] + c1_relb[128 + mm] + c1_relb[192 + mm];
        else               v = c1_relb[96 + mm] + c1_relb[160 + mm] + c1_relb[224 + mm];
        bcat[i] = v;
    }
    for (int i = gid; i < 128; i += gsz) bc2[i] = c2_relb[128 + i] + c2_relb[256 + i];

    for (int i = gid; i < 2048; i += gsz) {
        int n = i >> 3, j = i & 7;
        W0b_h[i] = (j < 7) ? f2b(wh_W0[j * 256 + n]) : f2b(b0h[n]);
        W0b_o[i] = (j < 7) ? f2b(wo_W0[j * 256 + n]) : f2b(b0o[n]);
        W0b_r[i] = (j < 6) ? f2b(wr_W0[j * 256 + n])
                 : (j == 6) ? f2b(b0r[n]) : (unsigned short)0;
    }
    // W1 fragments with PERMUTED rows (register-direct B-operand, R13)
    for (int i = gid; i < 32768; i += gsz) {
        int j = i & 7, l = (i >> 3) & 63, nt = (i >> 9) & 7, ks = i >> 12;
        int kk = ((j >> 2) * 8 + ks) * 16 + (l >> 4) * 4 + (j & 3);
        int n = nt * 16 + (l & 15);
        W1f_h[i] = f2b(wh_W1[kk * 128 + n]);
        W1f_o[i] = f2b(wo_W1[kk * 128 + n]);
        W1f_r[i] = f2b(wr_W1[kk * 128 + n]);
    }
    // Mf fragments with PERMUTED rows (register-direct B-operand, R13)
    for (int i = gid; i < 4096; i += gsz) {
        int j = i & 7, l = (i >> 3) & 63, nt = (i >> 9) & 1, ks = i >> 10;
        int kk = ((j >> 2) * 4 + ks) * 16 + (l >> 4) * 4 + (j & 3);
        int n = nt * 16 + (l & 15);
        int i0 = kk * 32 + n;
        Mf_h[i] = f2b(c1_rootW[i0] + c1_rootW[4*4096 + i0] + c1_rootW[6*4096 + i0] - c1_relW[6*4096 + i0]);
        Mf_o[i] = f2b(c1_rootW[3*4096 + i0] + c1_rootW[5*4096 + i0] + c1_rootW[7*4096 + i0] - c1_relW[7*4096 + i0]);
    }
    for (int i = gid; i < 36864; i += gsz) {
        int j = i & 7, l = (i >> 3) & 63, rem = i >> 9;
        int nt = rem % 6, ks = rem / 6;
        int k = ks * 32 + (l >> 4) * 8 + j;
        int n = nt * 16 + (l & 15);
        Wcatf[i] = f2b(wcat_val(k, n, c1_relW, c1_rootW));
    }
    for (int i = gid; i < 12288; i += gsz) {
        int j = i & 7, l = (i >> 3) & 63, rem = i >> 9;
        int nt = rem & 7, ks = rem >> 3;
        int k = ks * 32 + (l >> 4) * 8 + j;
        int n = nt * 16 + (l & 15);
        Wc2f[i] = f2b(wc2_val(k, n, c2_relW, c2_rootW));
    }
    for (int i = gid; i < 32768; i += gsz) {
        int j = i & 7, l = (i >> 3) & 63, rem = i >> 9;
        int nt = rem & 15, ks = rem >> 4;
        int k = ks * 32 + (l >> 4) * 8 + j;
        int n = nt * 16 + (l & 15);
        vW0f[i] = f2b(v_W0[k * 256 + n]);
    }
    for (int i = gid; i < 32768; i += gsz) {
        int j = i & 7, l = (i >> 3) & 63, rem = i >> 9;
        int nt = rem & 7, ks = rem >> 3;
        int k = ks * 32 + (l >> 4) * 8 + j;
        int n = nt * 16 + (l & 15);
        vW1f[i] = f2b(v_W1[k * 128 + n]);
    }
}

// ---------------------------------------------------------------------------
// mlp_blockE (R13): fully register-resident dataflow between the three MFMA
// stages. Layer-1 acc -> pack -> layer-2 B-operand DIRECTLY (W1f rows
// permuted); layer-2 acc -> pack -> t-MFMA B-operand DIRECTLY (Mf rows
// permuted). h never touches LDS; e touches LDS only for the per-b scan.
// LDS: W0s@0 4K | Mfs@4K 8K | W1s@12K 64K | b1s@77824 0.5K |
//      es@78336 8x4352 = 110.5K total.
// ---------------------------------------------------------------------------
#define SM_W0   0
#define SM_MF   4096
#define SM_W1   12288
#define SM_B1   77824
#define SM_HS   78336
#define SM_SZ   (78336 + 8 * 16 * 136 * 2)

template<int NPB, int NODE0, int INOFF, int INDIM, bool TAIL>
__device__ __forceinline__ void mlp_blockE(
    int blkrow0, const float* __restrict__ state,
    const unsigned short* __restrict__ W0b_g,
    const unsigned short* __restrict__ W1f_g, const float* __restrict__ b1,
    const unsigned short* __restrict__ Mf_g,
    unsigned short* __restrict__ tR, float* __restrict__ sumB,
    unsigned short* __restrict__ eR, char* smem)
{
    unsigned short* W0s = (unsigned short*)(smem + SM_W0);
    unsigned short* Mfs = (unsigned short*)(smem + SM_MF);
    unsigned short* W1s = (unsigned short*)(smem + SM_W1);
    float* b1s          = (float*)(smem + SM_B1);

    const int t = threadIdx.x;
    const int lane = t & 63;
    const int w = t >> 6;
    const int l15 = lane & 15;
    const int quad = lane >> 4;
    const int R0 = blkrow0 + w * 128;     // this wave's 128 contiguous rows
    unsigned short* ew = (unsigned short*)(smem + SM_HS) + w * (16 * 136); // [16][136]

    // ---- one-time staging ----
    if (t < 256) ((uint4*)W0s)[t] = ((const uint4*)W0b_g)[t];
    if (t >= 256 && t < 384) b1s[t - 256] = b1[t - 256];
    #pragma unroll
    for (int i = 0; i < 8; ++i)
        ((uint4*)W1s)[t + 512 * i] = ((const uint4*)W1f_g)[t + 512 * i];
    if constexpr (TAIL)
        ((uint4*)Mfs)[t] = ((const uint4*)Mf_g)[t];
    __syncthreads();   // the ONLY block-wide barrier

    // ---- layer-2 bias in registers (32 VGPR, pinned) ----
    f32x4 bias1[8];
    #pragma unroll
    for (int nt = 0; nt < 8; ++nt) {
        float4 bb = *(const float4*)(b1s + nt * 16 + quad * 4);
        bias1[nt] = pin_f4((f32x4){bb.x, bb.y, bb.z, bb.w});
    }

    float s0 = 0.f, s1 = 0.f;
    int bcur = R0 / NPB;

    // ---- X pipeline: load floats for sub 0 now; each sub prefetches sub+1 ----
    float xf[INDIM];
    #pragma unroll 1
    for (int dummy = 0; dummy < 1; ++dummy) {
        if (quad == 0) {
            int grow = R0 + l15;
            int b = grow / NPB;
            int n = grow - b * NPB + NODE0;
            const float* xp = state + ((size_t)b * NSTATE + n) * DIN + INOFF;
            #pragma unroll
            for (int j = 0; j < INDIM; ++j) xf[j] = xp[j];
        }
    }

    for (int sub = 0; sub < 8; ++sub) {
        const int wrow0 = R0 + sub * 16;

        // ---- X: convert current (bias slot k=INDIM gets 1.0), then issue
        // next sub's loads (latency hides under layer2 + tail) ----
        bf16x8 bx = {};
        if (quad == 0) {
            #pragma unroll
            for (int j = 0; j < INDIM; ++j)
                bx[j] = (short)f2b(xf[j]);
            bx[INDIM] = (short)0x3F80;   // 1.0bf16 multiplies the b0 A-slot
        }
        if (sub < 7 && quad == 0) {
            int grow = wrow0 + 16 + l15;
            int b = grow / NPB;
            int n = grow - b * NPB + NODE0;
            const float* xp = state + ((size_t)b * NSTATE + n) * DIN + INOFF;
            #pragma unroll
            for (int j = 0; j < INDIM; ++j) xf[j] = xp[j];
        }

        // ---- layer 1 (swapped): a1[nt][reg] = h[r=l15][n=nt*16+quad*4+reg];
        // bias via MFMA A-slot j=INDIM, acc starts at 0. Pure registers. ----
        f32x4 a1[16];
        #pragma unroll
        for (int nt = 0; nt < 16; ++nt) {
            bf16x8 aw = {};
            if (quad == 0)
                aw = *(const bf16x8*)(W0s + (nt * 16 + l15) * 8);
            f32x4 c = {0.f, 0.f, 0.f, 0.f};
            a1[nt] = __builtin_amdgcn_mfma_f32_16x16x32_bf16(aw, bx, c, 0, 0, 0);
        }

        // ---- pack h into layer-2 B-fragments IN REGISTERS (W1f rows are
        // permuted to match): bh[ks] slots = relu-bf16 of
        // a1[ks][0..3], a1[ks+8][0..3] ----
        bf16x8 bh[8];
        #pragma unroll
        for (int ks = 0; ks < 8; ++ks) {
            uint4 u;
            u.x = pack2(a1[ks][0], a1[ks][1]);
            u.y = pack2(a1[ks][2], a1[ks][3]);
            u.z = pack2(a1[ks + 8][0], a1[ks + 8][1]);
            u.w = pack2(a1[ks + 8][2], a1[ks + 8][3]);
            bh[ks] = __builtin_bit_cast(bf16x8, u);
        }

        // ---- layer 2 (swapped): acc[nt][reg] = e[r=l15][n=nt*16+quad*4+reg] ----
        f32x4 acc[8];
        #pragma unroll
        for (int nt = 0; nt < 8; ++nt) acc[nt] = bias1[nt];
        #pragma unroll
        for (int ks = 0; ks < 8; ++ks) {
            #pragma unroll
            for (int nt = 0; nt < 8; ++nt) {
                bf16x8 aw = *(const bf16x8*)(W1s + ((ks * 8 + nt) * 64 + lane) * 8);
                acc[nt] = __builtin_amdgcn_mfma_f32_16x16x32_bf16(aw, bh[ks], acc[nt], 0, 0, 0);
            }
        }

        // relu+pack e once; used by ew stores, t-MFMA B-fragments, eR stores
        uint2 pv[8];
        #pragma unroll
        for (int nt = 0; nt < 8; ++nt)
            pv[nt] = (uint2){pack2(acc[nt][0], acc[nt][1]), pack2(acc[nt][2], acc[nt][3])};

        if constexpr (TAIL) {
            // intra-wave WAR: prior sub's scan reads complete before overwrite
            __asm__ __volatile__("s_waitcnt lgkmcnt(0)" ::: "memory");
            #pragma unroll
            for (int nt = 0; nt < 8; ++nt)
                *(uint2*)(ew + l15 * 136 + nt * 16 + quad * 4) = pv[nt];

            // t = e @ M, SWAPPED (A=Mf frag permuted-rows, B=e from REGISTERS):
            // ae[ks] slots = relu-bf16 of acc[ks][0..3], acc[ks+4][0..3]
            f32x4 tacc[2] = {{0.f,0.f,0.f,0.f},{0.f,0.f,0.f,0.f}};
            #pragma unroll
            for (int ks = 0; ks < 4; ++ks) {
                uint4 ua;
                ua.x = pv[ks].x; ua.y = pv[ks].y;
                ua.z = pv[ks + 4].x; ua.w = pv[ks + 4].y;
                bf16x8 ae = __builtin_bit_cast(bf16x8, ua);
                #pragma unroll
                for (int nt = 0; nt < 2; ++nt) {
                    bf16x8 bm = *(const bf16x8*)(Mfs + ((ks * 2 + nt) * 64 + lane) * 8);
                    tacc[nt] = __builtin_amdgcn_mfma_f32_16x16x32_bf16(bm, ae, tacc[nt], 0, 0, 0);
                }
            }
            #pragma unroll
            for (int nt = 0; nt < 2; ++nt) {
                uint2 tv = {pack2n(tacc[nt][0], tacc[nt][1]), pack2n(tacc[nt][2], tacc[nt][3])};
                *(uint2*)(tR + (size_t)(wrow0 + l15) * 32 + nt * 16 + quad * 4) = tv;
            }

            // per-b sums in registers (cols 2*lane, 2*lane+1); flush at b bounds
            #pragma unroll
            for (int r = 0; r < 16; ++r) {
                int b = (wrow0 + r) / NPB;
                if (b != bcur) {
                    bool interior = (bcur * NPB >= R0) && ((bcur + 1) * NPB <= R0 + 128);
                    float* dst = sumB + (size_t)bcur * 128 + 2 * lane;
                    if (interior) { dst[0] = s0; dst[1] = s1; }
                    else { atomicAdd(dst, s0); atomicAdd(dst + 1, s1); }
                    s0 = 0.f; s1 = 0.f; bcur = b;
                }
                unsigned v = *(const unsigned*)(ew + r * 136 + lane * 2);
                s0 += b2f((unsigned short)v);
                s1 += b2f((unsigned short)(v >> 16));
            }
            if (sub == 7) {
                bool interior = (bcur * NPB >= R0) && ((bcur + 1) * NPB <= R0 + 128);
                float* dst = sumB + (size_t)bcur * 128 + 2 * lane;
                if (interior) { dst[0] = s0; dst[1] = s1; }
                else { atomicAdd(dst, s0); atomicAdd(dst + 1, s1); }
            }
        } else {
            // root: direct row-major global store eR[row][n]
            #pragma unroll
            for (int nt = 0; nt < 8; ++nt)
                *(uint2*)(eR + (size_t)(wrow0 + l15) * 128 + nt * 16 + quad * 4) = pv[nt];
        }
        __asm__ __volatile__("" ::: "memory");   // keep iteration LDS order
    }
}

__global__ __launch_bounds__(512, 2) void k_mlpE(
    const float* __restrict__ state,
    const unsigned short* __restrict__ W0b_h,
    const unsigned short* __restrict__ W1f_h, const float* __restrict__ b1_h,
    const unsigned short* __restrict__ Mf_h, unsigned short* __restrict__ tR_h,
    float* __restrict__ shB,
    const unsigned short* __restrict__ W0b_o,
    const unsigned short* __restrict__ W1f_o, const float* __restrict__ b1_o,
    const unsigned short* __restrict__ Mf_o, unsigned short* __restrict__ tR_o,
    float* __restrict__ soB,
    const unsigned short* __restrict__ W0b_r,
    const unsigned short* __restrict__ W1f_r, const float* __restrict__ b1_r,
    unsigned short* __restrict__ eR)
{
    __shared__ __align__(16) char smem[SM_SZ];
    int bid = blockIdx.x;
    if (bid < 160)
        mlp_blockE<20, 0, 6, 7, true>(bid * 1024, state, W0b_h, W1f_h, b1_h,
                                      Mf_h, tR_h, shB, nullptr, smem);
    else if (bid < 240)
        mlp_blockE<10, 20, 6, 7, true>((bid - 160) * 1024, state, W0b_o, W1f_o, b1_o,
                                       Mf_o, tR_o, soB, nullptr, smem);
    else
        mlp_blockE<1, 0, 0, 6, false>((bid - 240) * 1024, state, W0b_r, W1f_r, b1_r,
                                      nullptr, nullptr, nullptr, eR, smem);
}

// ---------------------------------------------------------------------------
// k_tail: FUSED u2 + sM + v, 16 b's per block, 512 blocks (2 blocks/CU,
// two independent barrier groups per CU). M=16 fills the MFMA exactly;
// N-tiles strided across the 4 waves.
// LDS 33KB: Ub[16][400] (V1b aliases) | Vb[16][104] | chL/coL | Hb | V2b
// ---------------------------------------------------------------------------
__global__ __launch_bounds__(256, 2) void k_tail(
    const unsigned short* __restrict__ eR,
    const float* __restrict__ shB, const float* __restrict__ soB,
    const unsigned short* __restrict__ tR_h, const unsigned short* __restrict__ tR_o,
    const unsigned short* __restrict__ Wcatf, const float* __restrict__ bcat,
    const unsigned short* __restrict__ Wc2f, const float* __restrict__ bc2,
    const unsigned short* __restrict__ vW0f, const float* __restrict__ vb0,
    const unsigned short* __restrict__ vW1f, const float* __restrict__ vb1,
    const float* __restrict__ vW2, const float* __restrict__ vb2,
    float* __restrict__ out)
{
    __shared__ __align__(16) char sm[33024];
    unsigned short* Ub  = (unsigned short*)(sm);          // [16][400]
    unsigned short* V1b = (unsigned short*)(sm);          // alias  [16][264]
    unsigned short* Vb  = (unsigned short*)(sm + 12800);  // [16][104]
    float* chL          = (float*)(sm + 16128);           // [16][32]
    float* coL          = (float*)(sm + 18176);           // [16][32]
    unsigned short* Hb  = (unsigned short*)(sm + 20224);  // [16][136]
    float* V2b          = (float*)(sm + 24576);           // [16][132]

    const int t = threadIdx.x, lane = t & 63, w = t >> 6;
    const int l15 = lane & 15, quad = lane >> 4;
    const int b0 = blockIdx.x * 16;
    const int rowb = quad * 4;

    // ---- phase 1: stage U = [er | sh | so] ----
    {
        int b = t >> 4, q = t & 15;
        ((uint4*)(Ub + b * 400))[q] = ((const uint4*)(eR + (size_t)(b0 + b) * 128))[q];
    }
    for (int idx = t; idx < 4096; idx += 256) {
        int b = idx >> 8, kk = idx & 255;
        float v = (kk < 128) ? shB[(size_t)(b0 + b) * 128 + kk]
                             : soB[(size_t)(b0 + b) * 128 + kk - 128];
        Ub[b * 400 + 128 + kk] = f2b(v);
    }
    __syncthreads();

    // ---- phase 2: U-MFMA (unswapped, verified): xr / ch / co ----
    for (int nt = w; nt < 6; nt += 4) {
        float bias = bcat[nt * 16 + l15];
        f32x4 acc = {bias, bias, bias, bias};
        #pragma unroll
        for (int ks = 0; ks < 12; ++ks) {
            bf16x8 a = *(const bf16x8*)(Ub + l15 * 400 + ks * 32 + quad * 8);
            bf16x8 bw = *(const bf16x8*)(Wcatf + ((ks * 6 + nt) * 64 + lane) * 8);
            acc = __builtin_amdgcn_mfma_f32_16x16x32_bf16(a, bw, acc, 0, 0, 0);
        }
        int n = nt * 16 + l15;
        #pragma unroll
        for (int reg = 0; reg < 4; ++reg) {
            float v = acc[reg];
            int b = rowb + reg;
            if (n < 32)      Vb[b * 104 + n] = f2b(fmaxf(v, 0.f));
            else if (n < 64) chL[b * 32 + (n - 32)] = v;
            else             coL[b * 32 + (n - 64)] = v;
        }
    }
    __syncthreads();

    // ---- phase 3: t-scan (row-major tR, coalesced) -> s2h, s2o ----
    for (int idx = t; idx < 512; idx += 256) {
        int b = idx >> 5, m = idx & 31;
        float ch = chL[b * 32 + m];
        const unsigned short* p = tR_h + (size_t)(b0 + b) * 20 * 32 + m;
        float s = 0.f;
        #pragma unroll
        for (int n = 0; n < 20; ++n) s += fmaxf(ch + b2f(p[n * 32]), 0.f);
        Vb[b * 104 + 32 + m] = f2b(s);
        float co = coL[b * 32 + m];
        const unsigned short* p2 = tR_o + (size_t)(b0 + b) * 10 * 32 + m;
        float s2 = 0.f;
        #pragma unroll
        for (int n = 0; n < 10; ++n) s2 += fmaxf(co + b2f(p2[n * 32]), 0.f);
        Vb[b * 104 + 64 + m] = f2b(s2);
    }
    __syncthreads();

    // ---- phase 4: c2 (N=128, 2 nt per wave) ----
    {
        f32x4 acc[2];
        #pragma unroll
        for (int q = 0; q < 2; ++q) {
            int nt = w + q * 4;
            float bias = bc2[nt * 16 + l15];
            acc[q] = (f32x4){bias, bias, bias, bias};
        }
        #pragma unroll
        for (int ks = 0; ks < 3; ++ks) {
            bf16x8 a = *(const bf16x8*)(Vb + l15 * 104 + ks * 32 + quad * 8);
            #pragma unroll
            for (int q = 0; q < 2; ++q) {
                int nt = w + q * 4;
                bf16x8 bw = *(const bf16x8*)(Wc2f + ((ks * 8 + nt) * 64 + lane) * 8);
                acc[q] = __builtin_amdgcn_mfma_f32_16x16x32_bf16(a, bw, acc[q], 0, 0, 0);
            }
        }
        #pragma unroll
        for (int q = 0; q < 2; ++q) {
            int nt = w + q * 4;
            #pragma unroll
            for (int reg = 0; reg < 4; ++reg)
                Hb[(rowb + reg) * 136 + nt * 16 + l15] = f2b(fmaxf(acc[q][reg], 0.f));
        }
    }
    __syncthreads();

    // ---- phase 5: v1 (N=256, 4 nt per wave; V1b aliases dead Ub) ----
    {
        f32x4 acc[4];
        #pragma unroll
        for (int q = 0; q < 4; ++q) {
            int nt = w + q * 4;
            float bias = vb0[nt * 16 + l15];
            acc[q] = (f32x4){bias, bias, bias, bias};
        }
        #pragma unroll
        for (int ks = 0; ks < 4; ++ks) {
            bf16x8 a = *(const bf16x8*)(Hb + l15 * 136 + ks * 32 + quad * 8);
            #pragma unroll
            for (int q = 0; q < 4; ++q) {
                int nt = w + q * 4;
                bf16x8 bw = *(const bf16x8*)(vW0f + ((ks * 16 + nt) * 64 + lane) * 8);
                acc[q] = __builtin_amdgcn_mfma_f32_16x16x32_bf16(a, bw, acc[q], 0, 0, 0);
            }
        }
        __syncthreads();   // Ub reads (phase-2 done long ago) -> safe; order vs writes
        #pragma unroll
        for (int q = 0; q < 4; ++q) {
            int nt = w + q * 4;
            #pragma unroll
            for (int reg = 0; reg < 4; ++reg)
                V1b[(rowb + reg) * 264 + nt * 16 + l15] = f2b(fmaxf(acc[q][reg], 0.f));
        }
    }
    __syncthreads();

    // ---- phase 6: v2 (N=128, 2 nt per wave) ----
    {
        f32x4 acc[2];
        #pragma unroll
        for (int q = 0; q < 2; ++q) {
            int nt = w + q * 4;
            float bias = vb1[nt * 16 + l15];
            acc[q] = (f32x4){bias, bias, bias, bias};
        }
        #pragma unroll
        for (int ks = 0; ks < 8; ++ks) {
            bf16x8 a = *(const bf16x8*)(V1b + l15 * 264 + ks * 32 + quad * 8);
            #pragma unroll
            for (int q = 0; q < 2; ++q) {
                int nt = w + q * 4;
                bf16x8 bw = *(const bf16x8*)(vW1f + ((ks * 8 + nt) * 64 + lane) * 8);
                acc[q] = __builtin_amdgcn_mfma_f32_16x16x32_bf16(a, bw, acc[q], 0, 0, 0);
            }
        }
        #pragma unroll
        for (int q = 0; q < 2; ++q) {
            int nt = w + q * 4;
            #pragma unroll
            for (int reg = 0; reg < 4; ++reg)
                V2b[(rowb + reg) * 132 + nt * 16 + l15] = fmaxf(acc[q][reg], 0.f);
        }
    }
    __syncthreads();

    // ---- phase 7: v3, 8 threads per b + shuffle reduce ----
    if (t < 128) {
        int b = t >> 3, j = t & 7;
        float v = 0.f;
        #pragma unroll
        for (int k = 0; k < 16; ++k)
            v = fmaf(V2b[b * 132 + j * 16 + k], vW2[j * 16 + k], v);
        v += __shfl_down(v, 4, 8);
        v += __shfl_down(v, 2, 8);
        v += __shfl_down(v, 1, 8);
        if (j == 0) out[b0 + b] = v + vb2[0];
    }
}

// ---------------------------------------------------------------------------
extern "C" void kernel_launch(void* const* d_in, const int* in_sizes, int n_in,
                              void* d_out, int out_size, void* d_ws, size_t ws_size,
                              hipStream_t stream)
{
    const float* state   = (const float*)d_in[0];
    const float* wr_W0   = (const float*)d_in[2];
    const float* wr_b0   = (const float*)d_in[3];
    const float* wr_W1   = (const float*)d_in[4];
    const float* wr_b1   = (const float*)d_in[5];
    const float* wh_W0   = (const float*)d_in[6];
    const float* wh_b0   = (const float*)d_in[7];
    const float* wh_W1   = (const float*)d_in[8];
    const float* wh_b1   = (const float*)d_in[9];
    const float* wo_W0   = (const float*)d_in[10];
    const float* wo_b0   = (const float*)d_in[11];
    const float* wo_W1   = (const float*)d_in[12];
    const float* wo_b1   = (const float*)d_in[13];
    const float* c1_relW = (const float*)d_in[14];
    const float* c1_relb = (const float*)d_in[15];
    const float* c1_rootW= (const float*)d_in[16];
    const float* c2_relW = (const float*)d_in[17];
    const float* c2_relb = (const float*)d_in[18];
    const float* c2_rootW= (const float*)d_in[19];
    const float* v_W0    = (const float*)d_in[20];
    const float* v_b0    = (const float*)d_in[21];
    const float* v_W1    = (const float*)d_in[22];
    const float* v_b1    = (const float*)d_in[23];
    const float* v_W2    = (const float*)d_in[24];
    const float* v_b2    = (const float*)d_in[25];

    char* ws = (char*)d_ws;
    size_t off = 0;
    auto alloc = [&](size_t bytes) -> char* {
        char* p = ws + off;
        off = (off + bytes + 255) & ~(size_t)255;
        return p;
    };
    float* shB  = (float*)alloc((size_t)BATCH * 128 * 4);          // b-major sums
    float* soB  = (float*)alloc((size_t)BATCH * 128 * 4);          // contiguous with shB
    unsigned short* tR_h = (unsigned short*)alloc((size_t)163840 * 32 * 2);  // row-major
    unsigned short* tR_o = (unsigned short*)alloc((size_t)81920 * 32 * 2);   // row-major
    unsigned short* eR   = (unsigned short*)alloc((size_t)BATCH * 128 * 2);
    float* bcat = (float*)alloc(96 * 4);
    float* bc2  = (float*)alloc(128 * 4);
    unsigned short* W0b_h = (unsigned short*)alloc(2048 * 2);
    unsigned short* W0b_o = (unsigned short*)alloc(2048 * 2);
    unsigned short* W0b_r = (unsigned short*)alloc(2048 * 2);
    unsigned short* W1f_h = (unsigned short*)alloc(32768 * 2);
    unsigned short* W1f_o = (unsigned short*)alloc(32768 * 2);
    unsigned short* W1f_r = (unsigned short*)alloc(32768 * 2);
    unsigned short* Mf_h  = (unsigned short*)alloc(4096 * 2);
    unsigned short* Mf_o  = (unsigned short*)alloc(4096 * 2);
    unsigned short* Wcatf = (unsigned short*)alloc(36864 * 2);
    unsigned short* Wc2f  = (unsigned short*)alloc(12288 * 2);
    unsigned short* vW0f  = (unsigned short*)alloc(32768 * 2);
    unsigned short* vW1f  = (unsigned short*)alloc(32768 * 2);
    (void)ws_size; (void)in_sizes; (void)n_in; (void)out_size;

    hipMemsetAsync(shB, 0, (size_t)2 * BATCH * 128 * 4, stream);

    k_prep<<<256, 256, 0, stream>>>(c1_relW, c1_relb, c1_rootW, c2_relW, c2_relb, c2_rootW,
                                    wh_W0, wh_W1, wo_W0, wo_W1, wr_W0, wr_W1, v_W0, v_W1,
                                    wh_b0, wo_b0, wr_b0,
                                    bcat, bc2, W0b_h, W0b_o, W0b_r, W1f_h, W1f_o, W1f_r,
                                    Mf_h, Mf_o, Wcatf, Wc2f, vW0f, vW1f);

    k_mlpE<<<248, 512, 0, stream>>>(state,
                                    W0b_h, W1f_h, wh_b1, Mf_h, tR_h, shB,
                                    W0b_o, W1f_o, wo_b1, Mf_o, tR_o, soB,
                                    W0b_r, W1f_r, wr_b1, eR);

    k_tail<<<512, 256, 0, stream>>>(eR, shB, soB, tR_h, tR_o,
                                    Wcatf, bcat, Wc2f, bc2, vW0f, v_b0, vW1f, v_b1,
                                    v_W2, v_b2, (float*)d_out);
}

// Round 4
// 157.457 us; speedup vs baseline: 1.0776x; 1.0452x over previous
//
#include <hip/hip_runtime.h>
#include <hip/hip_bf16.h>
#include <stdint.h>

#define BATCH 8192
#define NSTATE 30
#define DIN 13
#define E1 256
#define E2 128

typedef short bf16x8 __attribute__((ext_vector_type(8)));
typedef float f32x4 __attribute__((ext_vector_type(4)));
typedef __bf16 bf16x2_t __attribute__((ext_vector_type(2)));

// f32 -> bf16 bits, round-to-nearest-even (native cast; compiler emits
// v_cvt_pk_bf16_f32 for pairs -- bit-identical to the old manual RNE)
__device__ __forceinline__ unsigned short f2b(float f) {
    return __builtin_bit_cast(unsigned short, (__bf16)f);
}
__device__ __forceinline__ float b2f(unsigned short b) {
    return __uint_as_float((unsigned)b << 16);
}
__device__ __forceinline__ unsigned pack2(float a, float b) {     // relu+pack
    bf16x2_t v = {(__bf16)fmaxf(a, 0.f), (__bf16)fmaxf(b, 0.f)};
    return __builtin_bit_cast(unsigned, v);
}
__device__ __forceinline__ unsigned pack2n(float a, float b) {    // pack only
    bf16x2_t v = {(__bf16)a, (__bf16)b};
    return __builtin_bit_cast(unsigned, v);
}

__device__ __forceinline__ f32x4 pin_f4(f32x4 v) {
    uint4 u = __builtin_bit_cast(uint4, v);
    asm volatile("" : "+v"(u.x), "+v"(u.y), "+v"(u.z), "+v"(u.w));
    return __builtin_bit_cast(f32x4, u);
}

// combined conv1 weight values (derived R1, verified)
__device__ __forceinline__ float wcat_val(int k, int m, const float* relW, const float* rootW) {
    int part = k >> 7, c = k & 127, grp = m >> 5, mm = m & 31;
    int off = c * 32 + mm;
    if (part == 0) return (grp == 0) ? rootW[4096 + off] + rootW[8192 + off]
                        : (grp == 1) ? relW[off] : relW[3*4096 + off];
    if (part == 1) return (grp == 0) ? relW[1*4096 + off]
                        : (grp == 1) ? relW[6*4096 + off] : relW[5*4096 + off];
    return (grp == 0) ? relW[2*4096 + off]
         : (grp == 1) ? relW[4*4096 + off] : relW[7*4096 + off];
}
__device__ __forceinline__ float wc2_val(int k, int n, const float* relW, const float* rootW) {
    int grp = k >> 5, kk = k & 31;
    int off = kk * 128 + n;
    if (grp == 0) return rootW[4096 + off] + rootW[8192 + off];
    if (grp == 1) return relW[4096 + off];
    return relW[8192 + off];
}

// ---------------------------------------------------------------------------
// k_prep: bias vectors + ALL bf16 MFMA fragment tables (verified decode):
//   entry i -> j=i&7, l=(i>>3)&63, k = ks*32+(l>>4)*8+j, n = nt*16+(l&15)
// R12: W0b carries b0 in A-slot j==INDIM (bias-in-MFMA).
// R13: W1f rows and Mf rows are PERMUTED so layer-2 / t-MFMA B-operands come
// directly from the producing MFMA's accumulator registers (no LDS transpose):
//   W1f row k=ks*32+quad*8+j  <- original E1 row ((j>>2)*8+ks)*16+quad*4+(j&3)
//   Mf  row k=ks*32+quad*8+j  <- original E2 row ((j>>2)*4+ks)*16+quad*4+(j&3)
// ---------------------------------------------------------------------------
__global__ void k_prep(const float* __restrict__ c1_relW, const float* __restrict__ c1_relb,
                       const float* __restrict__ c1_rootW,
                       const float* __restrict__ c2_relW, const float* __restrict__ c2_relb,
                       const float* __restrict__ c2_rootW,
                       const float* __restrict__ wh_W0, const float* __restrict__ wh_W1,
                       const float* __restrict__ wo_W0, const float* __restrict__ wo_W1,
                       const float* __restrict__ wr_W0, const float* __restrict__ wr_W1,
                       const float* __restrict__ v_W0, const float* __restrict__ v_W1,
                       const float* __restrict__ b0h, const float* __restrict__ b0o,
                       const float* __restrict__ b0r,
                       float* __restrict__ bcat, float* __restrict__ bc2,
                       unsigned short* __restrict__ W0b_h, unsigned short* __restrict__ W0b_o,
                       unsigned short* __restrict__ W0b_r,
                       unsigned short* __restrict__ W1f_h, unsigned short* __restrict__ W1f_o,
                       unsigned short* __restrict__ W1f_r,
                       unsigned short* __restrict__ Mf_h, unsigned short* __restrict__ Mf_o,
                       unsigned short* __restrict__ Wcatf, unsigned short* __restrict__ Wc2f,
                       unsigned short* __restrict__ vW0f, unsigned short* __restrict__ vW1f)
{
    int gid = blockIdx.x * blockDim.x + threadIdx.x;
    int gsz = gridDim.x * blockDim.x;

    for (int i = gid; i < 96; i += gsz) {
        int grp = i >> 5, mm = i & 31;
        float v;
        if (grp == 0)      v = c1_relb[32 + mm] + c1_relb[64 + mm];
        else if (grp == 1) v = c1_relb[mm] + c1_relb[128 + mm] + c1_relb[192 + mm];
        else               v = c1_relb[96 + mm] + c1_relb[160 + mm] + c1_relb[224 + mm];
        bcat[i] = v;
    }
    for (int i = gid; i < 128; i += gsz) bc2[i] = c2_relb[128 + i] + c2_relb[256 + i];

    for (int i = gid; i < 2048; i += gsz) {
        int n = i >> 3, j = i & 7;
        W0b_h[i] = (j < 7) ? f2b(wh_W0[j * 256 + n]) : f2b(b0h[n]);
        W0b_o[i] = (j < 7) ? f2b(wo_W0[j * 256 + n]) : f2b(b0o[n]);
        W0b_r[i] = (j < 6) ? f2b(wr_W0[j * 256 + n])
                 : (j == 6) ? f2b(b0r[n]) : (unsigned short)0;
    }
    // W1 fragments with PERMUTED rows (register-direct B-operand, R13)
    for (int i = gid; i < 32768; i += gsz) {
        int j = i & 7, l = (i >> 3) & 63, nt = (i >> 9) & 7, ks = i >> 12;
        int kk = ((j >> 2) * 8 + ks) * 16 + (l >> 4) * 4 + (j & 3);
        int n = nt * 16 + (l & 15);
        W1f_h[i] = f2b(wh_W1[kk * 128 + n]);
        W1f_o[i] = f2b(wo_W1[kk * 128 + n]);
        W1f_r[i] = f2b(wr_W1[kk * 128 + n]);
    }
    // Mf fragments with PERMUTED rows (register-direct B-operand, R13)
    for (int i = gid; i < 4096; i += gsz) {
        int j = i & 7, l = (i >> 3) & 63, nt = (i >> 9) & 1, ks = i >> 10;
        int kk = ((j >> 2) * 4 + ks) * 16 + (l >> 4) * 4 + (j & 3);
        int n = nt * 16 + (l & 15);
        int i0 = kk * 32 + n;
        Mf_h[i] = f2b(c1_rootW[i0] + c1_rootW[4*4096 + i0] + c1_rootW[6*4096 + i0] - c1_relW[6*4096 + i0]);
        Mf_o[i] = f2b(c1_rootW[3*4096 + i0] + c1_rootW[5*4096 + i0] + c1_rootW[7*4096 + i0] - c1_relW[7*4096 + i0]);
    }
    for (int i = gid; i < 36864; i += gsz) {
        int j = i & 7, l = (i >> 3) & 63, rem = i >> 9;
        int nt = rem % 6, ks = rem / 6;
        int k = ks * 32 + (l >> 4) * 8 + j;
        int n = nt * 16 + (l & 15);
        Wcatf[i] = f2b(wcat_val(k, n, c1_relW, c1_rootW));
    }
    for (int i = gid; i < 12288; i += gsz) {
        int j = i & 7, l = (i >> 3) & 63, rem = i >> 9;
        int nt = rem & 7, ks = rem >> 3;
        int k = ks * 32 + (l >> 4) * 8 + j;
        int n = nt * 16 + (l & 15);
        Wc2f[i] = f2b(wc2_val(k, n, c2_relW, c2_rootW));
    }
    for (int i = gid; i < 32768; i += gsz) {
        int j = i & 7, l = (i >> 3) & 63, rem = i >> 9;
        int nt = rem & 15, ks = rem >> 4;
        int k = ks * 32 + (l >> 4) * 8 + j;
        int n = nt * 16 + (l & 15);
        vW0f[i] = f2b(v_W0[k * 256 + n]);
    }
    for (int i = gid; i < 32768; i += gsz) {
        int j = i & 7, l = (i >> 3) & 63, rem = i >> 9;
        int nt = rem & 7, ks = rem >> 3;
        int k = ks * 32 + (l >> 4) * 8 + j;
        int n = nt * 16 + (l & 15);
        vW1f[i] = f2b(v_W1[k * 128 + n]);
    }
}

// ---------------------------------------------------------------------------
// mlp_blockE (R14): register-resident dataflow (R13) at DOUBLE occupancy.
// Blocks are now 1024 threads = 16 waves x 64 rows (was 8 x 128): same grid,
// same per-wave code with 4 subs, same total LDS traffic / MFMA count, but
// 4 waves/SIMD instead of 2 to hide the dependency-chain latency that R1-R3
// showed was the bottleneck (all pipes <30% busy, timing insensitive to
// instruction removal).
// LDS: W0s@0 4K | Mfs@4K 8K | W1s@12K 64K | b1s@77824 0.5K |
//      es@78336 16x4352 = 144.5K total (1 block/CU, 16 waves).
// ---------------------------------------------------------------------------
#define SM_W0   0
#define SM_MF   4096
#define SM_W1   12288
#define SM_B1   77824
#define SM_HS   78336
#define SM_SZ   (78336 + 16 * 16 * 136 * 2)

template<int NPB, int NODE0, int INOFF, int INDIM, bool TAIL>
__device__ __forceinline__ void mlp_blockE(
    int blkrow0, const float* __restrict__ state,
    const unsigned short* __restrict__ W0b_g,
    const unsigned short* __restrict__ W1f_g, const float* __restrict__ b1,
    const unsigned short* __restrict__ Mf_g,
    unsigned short* __restrict__ tR, float* __restrict__ sumB,
    unsigned short* __restrict__ eR, char* smem)
{
    unsigned short* W0s = (unsigned short*)(smem + SM_W0);
    unsigned short* Mfs = (unsigned short*)(smem + SM_MF);
    unsigned short* W1s = (unsigned short*)(smem + SM_W1);
    float* b1s          = (float*)(smem + SM_B1);

    const int t = threadIdx.x;
    const int lane = t & 63;
    const int w = t >> 6;
    const int l15 = lane & 15;
    const int quad = lane >> 4;
    const int R0 = blkrow0 + w * 64;      // this wave's 64 contiguous rows
    unsigned short* ew = (unsigned short*)(smem + SM_HS) + w * (16 * 136); // [16][136]

    // ---- one-time staging (1024 threads) ----
    if (t < 256) ((uint4*)W0s)[t] = ((const uint4*)W0b_g)[t];
    if (t >= 256 && t < 384) b1s[t - 256] = b1[t - 256];
    #pragma unroll
    for (int i = 0; i < 4; ++i)
        ((uint4*)W1s)[t + 1024 * i] = ((const uint4*)W1f_g)[t + 1024 * i];
    if constexpr (TAIL) {
        if (t >= 512 && t < 1024) ((uint4*)Mfs)[t - 512] = ((const uint4*)Mf_g)[t - 512];
    }
    __syncthreads();   // the ONLY block-wide barrier

    // ---- layer-2 bias in registers (32 VGPR, pinned) ----
    f32x4 bias1[8];
    #pragma unroll
    for (int nt = 0; nt < 8; ++nt) {
        float4 bb = *(const float4*)(b1s + nt * 16 + quad * 4);
        bias1[nt] = pin_f4((f32x4){bb.x, bb.y, bb.z, bb.w});
    }

    float s0 = 0.f, s1 = 0.f;
    int bcur = R0 / NPB;

    // ---- X pipeline: load floats for sub 0 now; each sub prefetches sub+1 ----
    float xf[INDIM];
    #pragma unroll 1
    for (int dummy = 0; dummy < 1; ++dummy) {
        if (quad == 0) {
            int grow = R0 + l15;
            int b = grow / NPB;
            int n = grow - b * NPB + NODE0;
            const float* xp = state + ((size_t)b * NSTATE + n) * DIN + INOFF;
            #pragma unroll
            for (int j = 0; j < INDIM; ++j) xf[j] = xp[j];
        }
    }

    for (int sub = 0; sub < 4; ++sub) {
        const int wrow0 = R0 + sub * 16;

        // ---- X: convert current (bias slot k=INDIM gets 1.0), then issue
        // next sub's loads (latency hides under layer2 + tail) ----
        bf16x8 bx = {};
        if (quad == 0) {
            #pragma unroll
            for (int j = 0; j < INDIM; ++j)
                bx[j] = (short)f2b(xf[j]);
            bx[INDIM] = (short)0x3F80;   // 1.0bf16 multiplies the b0 A-slot
        }
        if (sub < 3 && quad == 0) {
            int grow = wrow0 + 16 + l15;
            int b = grow / NPB;
            int n = grow - b * NPB + NODE0;
            const float* xp = state + ((size_t)b * NSTATE + n) * DIN + INOFF;
            #pragma unroll
            for (int j = 0; j < INDIM; ++j) xf[j] = xp[j];
        }

        // ---- layer 1 (swapped): a1[nt][reg] = h[r=l15][n=nt*16+quad*4+reg];
        // bias via MFMA A-slot j=INDIM, acc starts at 0. Pure registers. ----
        f32x4 a1[16];
        #pragma unroll
        for (int nt = 0; nt < 16; ++nt) {
            bf16x8 aw = {};
            if (quad == 0)
                aw = *(const bf16x8*)(W0s + (nt * 16 + l15) * 8);
            f32x4 c = {0.f, 0.f, 0.f, 0.f};
            a1[nt] = __builtin_amdgcn_mfma_f32_16x16x32_bf16(aw, bx, c, 0, 0, 0);
        }

        // ---- pack h into layer-2 B-fragments IN REGISTERS (W1f rows are
        // permuted to match): bh[ks] slots = relu-bf16 of
        // a1[ks][0..3], a1[ks+8][0..3] ----
        bf16x8 bh[8];
        #pragma unroll
        for (int ks = 0; ks < 8; ++ks) {
            uint4 u;
            u.x = pack2(a1[ks][0], a1[ks][1]);
            u.y = pack2(a1[ks][2], a1[ks][3]);
            u.z = pack2(a1[ks + 8][0], a1[ks + 8][1]);
            u.w = pack2(a1[ks + 8][2], a1[ks + 8][3]);
            bh[ks] = __builtin_bit_cast(bf16x8, u);
        }

        // ---- layer 2 (swapped): acc[nt][reg] = e[r=l15][n=nt*16+quad*4+reg] ----
        f32x4 acc[8];
        #pragma unroll
        for (int nt = 0; nt < 8; ++nt) acc[nt] = bias1[nt];
        #pragma unroll
        for (int ks = 0; ks < 8; ++ks) {
            #pragma unroll
            for (int nt = 0; nt < 8; ++nt) {
                bf16x8 aw = *(const bf16x8*)(W1s + ((ks * 8 + nt) * 64 + lane) * 8);
                acc[nt] = __builtin_amdgcn_mfma_f32_16x16x32_bf16(aw, bh[ks], acc[nt], 0, 0, 0);
            }
        }

        // relu+pack e once; used by ew stores, t-MFMA B-fragments, eR stores
        uint2 pv[8];
        #pragma unroll
        for (int nt = 0; nt < 8; ++nt)
            pv[nt] = (uint2){pack2(acc[nt][0], acc[nt][1]), pack2(acc[nt][2], acc[nt][3])};

        if constexpr (TAIL) {
            // intra-wave WAR: prior sub's scan reads complete before overwrite
            __asm__ __volatile__("s_waitcnt lgkmcnt(0)" ::: "memory");
            #pragma unroll
            for (int nt = 0; nt < 8; ++nt)
                *(uint2*)(ew + l15 * 136 + nt * 16 + quad * 4) = pv[nt];

            // t = e @ M, SWAPPED (A=Mf frag permuted-rows, B=e from REGISTERS):
            // ae[ks] slots = relu-bf16 of acc[ks][0..3], acc[ks+4][0..3]
            f32x4 tacc[2] = {{0.f,0.f,0.f,0.f},{0.f,0.f,0.f,0.f}};
            #pragma unroll
            for (int ks = 0; ks < 4; ++ks) {
                uint4 ua;
                ua.x = pv[ks].x; ua.y = pv[ks].y;
                ua.z = pv[ks + 4].x; ua.w = pv[ks + 4].y;
                bf16x8 ae = __builtin_bit_cast(bf16x8, ua);
                #pragma unroll
                for (int nt = 0; nt < 2; ++nt) {
                    bf16x8 bm = *(const bf16x8*)(Mfs + ((ks * 2 + nt) * 64 + lane) * 8);
                    tacc[nt] = __builtin_amdgcn_mfma_f32_16x16x32_bf16(bm, ae, tacc[nt], 0, 0, 0);
                }
            }
            #pragma unroll
            for (int nt = 0; nt < 2; ++nt) {
                uint2 tv = {pack2n(tacc[nt][0], tacc[nt][1]), pack2n(tacc[nt][2], tacc[nt][3])};
                *(uint2*)(tR + (size_t)(wrow0 + l15) * 32 + nt * 16 + quad * 4) = tv;
            }

            // per-b sums in registers (cols 2*lane, 2*lane+1); flush at b bounds
            #pragma unroll
            for (int r = 0; r < 16; ++r) {
                int b = (wrow0 + r) / NPB;
                if (b != bcur) {
                    bool interior = (bcur * NPB >= R0) && ((bcur + 1) * NPB <= R0 + 64);
                    float* dst = sumB + (size_t)bcur * 128 + 2 * lane;
                    if (interior) { dst[0] = s0; dst[1] = s1; }
                    else { atomicAdd(dst, s0); atomicAdd(dst + 1, s1); }
                    s0 = 0.f; s1 = 0.f; bcur = b;
                }
                unsigned v = *(const unsigned*)(ew + r * 136 + lane * 2);
                s0 += b2f((unsigned short)v);
                s1 += b2f((unsigned short)(v >> 16));
            }
            if (sub == 3) {
                bool interior = (bcur * NPB >= R0) && ((bcur + 1) * NPB <= R0 + 64);
                float* dst = sumB + (size_t)bcur * 128 + 2 * lane;
                if (interior) { dst[0] = s0; dst[1] = s1; }
                else { atomicAdd(dst, s0); atomicAdd(dst + 1, s1); }
            }
        } else {
            // root: direct row-major global store eR[row][n]
            #pragma unroll
            for (int nt = 0; nt < 8; ++nt)
                *(uint2*)(eR + (size_t)(wrow0 + l15) * 128 + nt * 16 + quad * 4) = pv[nt];
        }
        __asm__ __volatile__("" ::: "memory");   // keep iteration LDS order
    }
}

__global__ __launch_bounds__(1024, 1) void k_mlpE(
    const float* __restrict__ state,
    const unsigned short* __restrict__ W0b_h,
    const unsigned short* __restrict__ W1f_h, const float* __restrict__ b1_h,
    const unsigned short* __restrict__ Mf_h, unsigned short* __restrict__ tR_h,
    float* __restrict__ shB,
    const unsigned short* __restrict__ W0b_o,
    const unsigned short* __restrict__ W1f_o, const float* __restrict__ b1_o,
    const unsigned short* __restrict__ Mf_o, unsigned short* __restrict__ tR_o,
    float* __restrict__ soB,
    const unsigned short* __restrict__ W0b_r,
    const unsigned short* __restrict__ W1f_r, const float* __restrict__ b1_r,
    unsigned short* __restrict__ eR)
{
    __shared__ __align__(16) char smem[SM_SZ];
    int bid = blockIdx.x;
    if (bid < 160)
        mlp_blockE<20, 0, 6, 7, true>(bid * 1024, state, W0b_h, W1f_h, b1_h,
                                      Mf_h, tR_h, shB, nullptr, smem);
    else if (bid < 240)
        mlp_blockE<10, 20, 6, 7, true>((bid - 160) * 1024, state, W0b_o, W1f_o, b1_o,
                                       Mf_o, tR_o, soB, nullptr, smem);
    else
        mlp_blockE<1, 0, 0, 6, false>((bid - 240) * 1024, state, W0b_r, W1f_r, b1_r,
                                      nullptr, nullptr, nullptr, eR, smem);
}

// ---------------------------------------------------------------------------
// k_tail: FUSED u2 + sM + v, 16 b's per block, 512 blocks (2 blocks/CU,
// two independent barrier groups per CU). M=16 fills the MFMA exactly;
// N-tiles strided across the 4 waves.
// LDS 33KB: Ub[16][400] (V1b aliases) | Vb[16][104] | chL/coL | Hb | V2b
// ---------------------------------------------------------------------------
__global__ __launch_bounds__(256, 2) void k_tail(
    const unsigned short* __restrict__ eR,
    const float* __restrict__ shB, const float* __restrict__ soB,
    const unsigned short* __restrict__ tR_h, const unsigned short* __restrict__ tR_o,
    const unsigned short* __restrict__ Wcatf, const float* __restrict__ bcat,
    const unsigned short* __restrict__ Wc2f, const float* __restrict__ bc2,
    const unsigned short* __restrict__ vW0f, const float* __restrict__ vb0,
    const unsigned short* __restrict__ vW1f, const float* __restrict__ vb1,
    const float* __restrict__ vW2, const float* __restrict__ vb2,
    float* __restrict__ out)
{
    __shared__ __align__(16) char sm[33024];
    unsigned short* Ub  = (unsigned short*)(sm);          // [16][400]
    unsigned short* V1b = (unsigned short*)(sm);          // alias  [16][264]
    unsigned short* Vb  = (unsigned short*)(sm + 12800);  // [16][104]
    float* chL          = (float*)(sm + 16128);           // [16][32]
    float* coL          = (float*)(sm + 18176);           // [16][32]
    unsigned short* Hb  = (unsigned short*)(sm + 20224);  // [16][136]
    float* V2b          = (float*)(sm + 24576);           // [16][132]

    const int t = threadIdx.x, lane = t & 63, w = t >> 6;
    const int l15 = lane & 15, quad = lane >> 4;
    const int b0 = blockIdx.x * 16;
    const int rowb = quad * 4;

    // ---- phase 1: stage U = [er | sh | so] ----
    {
        int b = t >> 4, q = t & 15;
        ((uint4*)(Ub + b * 400))[q] = ((const uint4*)(eR + (size_t)(b0 + b) * 128))[q];
    }
    for (int idx = t; idx < 4096; idx += 256) {
        int b = idx >> 8, kk = idx & 255;
        float v = (kk < 128) ? shB[(size_t)(b0 + b) * 128 + kk]
                             : soB[(size_t)(b0 + b) * 128 + kk - 128];
        Ub[b * 400 + 128 + kk] = f2b(v);
    }
    __syncthreads();

    // ---- phase 2: U-MFMA (unswapped, verified): xr / ch / co ----
    for (int nt = w; nt < 6; nt += 4) {
        float bias = bcat[nt * 16 + l15];
        f32x4 acc = {bias, bias, bias, bias};
        #pragma unroll
        for (int ks = 0; ks < 12; ++ks) {
            bf16x8 a = *(const bf16x8*)(Ub + l15 * 400 + ks * 32 + quad * 8);
            bf16x8 bw = *(const bf16x8*)(Wcatf + ((ks * 6 + nt) * 64 + lane) * 8);
            acc = __builtin_amdgcn_mfma_f32_16x16x32_bf16(a, bw, acc, 0, 0, 0);
        }
        int n = nt * 16 + l15;
        #pragma unroll
        for (int reg = 0; reg < 4; ++reg) {
            float v = acc[reg];
            int b = rowb + reg;
            if (n < 32)      Vb[b * 104 + n] = f2b(fmaxf(v, 0.f));
            else if (n < 64) chL[b * 32 + (n - 32)] = v;
            else             coL[b * 32 + (n - 64)] = v;
        }
    }
    __syncthreads();

    // ---- phase 3: t-scan (row-major tR, coalesced) -> s2h, s2o ----
    for (int idx = t; idx < 512; idx += 256) {
        int b = idx >> 5, m = idx & 31;
        float ch = chL[b * 32 + m];
        const unsigned short* p = tR_h + (size_t)(b0 + b) * 20 * 32 + m;
        float s = 0.f;
        #pragma unroll
        for (int n = 0; n < 20; ++n) s += fmaxf(ch + b2f(p[n * 32]), 0.f);
        Vb[b * 104 + 32 + m] = f2b(s);
        float co = coL[b * 32 + m];
        const unsigned short* p2 = tR_o + (size_t)(b0 + b) * 10 * 32 + m;
        float s2 = 0.f;
        #pragma unroll
        for (int n = 0; n < 10; ++n) s2 += fmaxf(co + b2f(p2[n * 32]), 0.f);
        Vb[b * 104 + 64 + m] = f2b(s2);
    }
    __syncthreads();

    // ---- phase 4: c2 (N=128, 2 nt per wave) ----
    {
        f32x4 acc[2];
        #pragma unroll
        for (int q = 0; q < 2; ++q) {
            int nt = w + q * 4;
            float bias = bc2[nt * 16 + l15];
            acc[q] = (f32x4){bias, bias, bias, bias};
        }
        #pragma unroll
        for (int ks = 0; ks < 3; ++ks) {
            bf16x8 a = *(const bf16x8*)(Vb + l15 * 104 + ks * 32 + quad * 8);
            #pragma unroll
            for (int q = 0; q < 2; ++q) {
                int nt = w + q * 4;
                bf16x8 bw = *(const bf16x8*)(Wc2f + ((ks * 8 + nt) * 64 + lane) * 8);
                acc[q] = __builtin_amdgcn_mfma_f32_16x16x32_bf16(a, bw, acc[q], 0, 0, 0);
            }
        }
        #pragma unroll
        for (int q = 0; q < 2; ++q) {
            int nt = w + q * 4;
            #pragma unroll
            for (int reg = 0; reg < 4; ++reg)
                Hb[(rowb + reg) * 136 + nt * 16 + l15] = f2b(fmaxf(acc[q][reg], 0.f));
        }
    }
    __syncthreads();

    // ---- phase 5: v1 (N=256, 4 nt per wave; V1b aliases dead Ub) ----
    {
        f32x4 acc[4];
        #pragma unroll
        for (int q = 0; q < 4; ++q) {
            int nt = w + q * 4;
            float bias = vb0[nt * 16 + l15];
            acc[q] = (f32x4){bias, bias, bias, bias};
        }
        #pragma unroll
        for (int ks = 0; ks < 4; ++ks) {
            bf16x8 a = *(const bf16x8*)(Hb + l15 * 136 + ks * 32 + quad * 8);
            #pragma unroll
            for (int q = 0; q < 4; ++q) {
                int nt = w + q * 4;
                bf16x8 bw = *(const bf16x8*)(vW0f + ((ks * 16 + nt) * 64 + lane) * 8);
                acc[q] = __builtin_amdgcn_mfma_f32_16x16x32_bf16(a, bw, acc[q], 0, 0, 0);
            }
        }
        __syncthreads();   // Ub reads (phase-2 done long ago) -> safe; order vs writes
        #pragma unroll
        for (int q = 0; q < 4; ++q) {
            int nt = w + q * 4;
            #pragma unroll
            for (int reg = 0; reg < 4; ++reg)
                V1b[(rowb + reg) * 264 + nt * 16 + l15] = f2b(fmaxf(acc[q][reg], 0.f));
        }
    }
    __syncthreads();

    // ---- phase 6: v2 (N=128, 2 nt per wave) ----
    {
        f32x4 acc[2];
        #pragma unroll
        for (int q = 0; q < 2; ++q) {
            int nt = w + q * 4;
            float bias = vb1[nt * 16 + l15];
            acc[q] = (f32x4){bias, bias, bias, bias};
        }
        #pragma unroll
        for (int ks = 0; ks < 8; ++ks) {
            bf16x8 a = *(const bf16x8*)(V1b + l15 * 264 + ks * 32 + quad * 8);
            #pragma unroll
            for (int q = 0; q < 2; ++q) {
                int nt = w + q * 4;
                bf16x8 bw = *(const bf16x8*)(vW1f + ((ks * 8 + nt) * 64 + lane) * 8);
                acc[q] = __builtin_amdgcn_mfma_f32_16x16x32_bf16(a, bw, acc[q], 0, 0, 0);
            }
        }
        #pragma unroll
        for (int q = 0; q < 2; ++q) {
            int nt = w + q * 4;
            #pragma unroll
            for (int reg = 0; reg < 4; ++reg)
                V2b[(rowb + reg) * 132 + nt * 16 + l15] = fmaxf(acc[q][reg], 0.f);
        }
    }
    __syncthreads();

    // ---- phase 7: v3, 8 threads per b + shuffle reduce ----
    if (t < 128) {
        int b = t >> 3, j = t & 7;
        float v = 0.f;
        #pragma unroll
        for (int k = 0; k < 16; ++k)
            v = fmaf(V2b[b * 132 + j * 16 + k], vW2[j * 16 + k], v);
        v += __shfl_down(v, 4, 8);
        v += __shfl_down(v, 2, 8);
        v += __shfl_down(v, 1, 8);
        if (j == 0) out[b0 + b] = v + vb2[0];
    }
}

// ---------------------------------------------------------------------------
extern "C" void kernel_launch(void* const* d_in, const int* in_sizes, int n_in,
                              void* d_out, int out_size, void* d_ws, size_t ws_size,
                              hipStream_t stream)
{
    const float* state   = (const float*)d_in[0];
    const float* wr_W0   = (const float*)d_in[2];
    const float* wr_b0   = (const float*)d_in[3];
    const float* wr_W1   = (const float*)d_in[4];
    const float* wr_b1   = (const float*)d_in[5];
    const float* wh_W0   = (const float*)d_in[6];
    const float* wh_b0   = (const float*)d_in[7];
    const float* wh_W1   = (const float*)d_in[8];
    const float* wh_b1   = (const float*)d_in[9];
    const float* wo_W0   = (const float*)d_in[10];
    const float* wo_b0   = (const float*)d_in[11];
    const float* wo_W1   = (const float*)d_in[12];
    const float* wo_b1   = (const float*)d_in[13];
    const float* c1_relW = (const float*)d_in[14];
    const float* c1_relb = (const float*)d_in[15];
    const float* c1_rootW= (const float*)d_in[16];
    const float* c2_relW = (const float*)d_in[17];
    const float* c2_relb = (const float*)d_in[18];
    const float* c2_rootW= (const float*)d_in[19];
    const float* v_W0    = (const float*)d_in[20];
    const float* v_b0    = (const float*)d_in[21];
    const float* v_W1    = (const float*)d_in[22];
    const float* v_b1    = (const float*)d_in[23];
    const float* v_W2    = (const float*)d_in[24];
    const float* v_b2    = (const float*)d_in[25];

    char* ws = (char*)d_ws;
    size_t off = 0;
    auto alloc = [&](size_t bytes) -> char* {
        char* p = ws + off;
        off = (off + bytes + 255) & ~(size_t)255;
        return p;
    };
    float* shB  = (float*)alloc((size_t)BATCH * 128 * 4);          // b-major sums
    float* soB  = (float*)alloc((size_t)BATCH * 128 * 4);          // contiguous with shB
    unsigned short* tR_h = (unsigned short*)alloc((size_t)163840 * 32 * 2);  // row-major
    unsigned short* tR_o = (unsigned short*)alloc((size_t)81920 * 32 * 2);   // row-major
    unsigned short* eR   = (unsigned short*)alloc((size_t)BATCH * 128 * 2);
    float* bcat = (float*)alloc(96 * 4);
    float* bc2  = (float*)alloc(128 * 4);
    unsigned short* W0b_h = (unsigned short*)alloc(2048 * 2);
    unsigned short* W0b_o = (unsigned short*)alloc(2048 * 2);
    unsigned short* W0b_r = (unsigned short*)alloc(2048 * 2);
    unsigned short* W1f_h = (unsigned short*)alloc(32768 * 2);
    unsigned short* W1f_o = (unsigned short*)alloc(32768 * 2);
    unsigned short* W1f_r = (unsigned short*)alloc(32768 * 2);
    unsigned short* Mf_h  = (unsigned short*)alloc(4096 * 2);
    unsigned short* Mf_o  = (unsigned short*)alloc(4096 * 2);
    unsigned short* Wcatf = (unsigned short*)alloc(36864 * 2);
    unsigned short* Wc2f  = (unsigned short*)alloc(12288 * 2);
    unsigned short* vW0f  = (unsigned short*)alloc(32768 * 2);
    unsigned short* vW1f  = (unsigned short*)alloc(32768 * 2);
    (void)ws_size; (void)in_sizes; (void)n_in; (void)out_size;

    hipMemsetAsync(shB, 0, (size_t)2 * BATCH * 128 * 4, stream);

    k_prep<<<256, 256, 0, stream>>>(c1_relW, c1_relb, c1_rootW, c2_relW, c2_relb, c2_rootW,
                                    wh_W0, wh_W1, wo_W0, wo_W1, wr_W0, wr_W1, v_W0, v_W1,
                                    wh_b0, wo_b0, wr_b0,
                                    bcat, bc2, W0b_h, W0b_o, W0b_r, W1f_h, W1f_o, W1f_r,
                                    Mf_h, Mf_o, Wcatf, Wc2f, vW0f, vW1f);

    k_mlpE<<<248, 1024, 0, stream>>>(state,
                                     W0b_h, W1f_h, wh_b1, Mf_h, tR_h, shB,
                                     W0b_o, W1f_o, wo_b1, Mf_o, tR_o, soB,
                                     W0b_r, W1f_r, wr_b1, eR);

    k_tail<<<512, 256, 0, stream>>>(eR, shB, soB, tR_h, tR_o,
                                    Wcatf, bcat, Wc2f, bc2, vW0f, v_b0, vW1f, v_b1,
                                    v_W2, v_b2, (float*)d_out);
}

// Round 5
// 153.268 us; speedup vs baseline: 1.1070x; 1.0273x over previous
//
#include <hip/hip_runtime.h>
#include <hip/hip_bf16.h>
#include <stdint.h>

#define BATCH 8192
#define NSTATE 30
#define DIN 13
#define E1 256
#define E2 128

typedef short bf16x8 __attribute__((ext_vector_type(8)));
typedef float f32x4 __attribute__((ext_vector_type(4)));
typedef float f32x16 __attribute__((ext_vector_type(16)));
typedef __bf16 bf16x2_t __attribute__((ext_vector_type(2)));

// f32 -> bf16 bits, round-to-nearest-even (native cast -> v_cvt_pk_bf16_f32)
__device__ __forceinline__ unsigned short f2b(float f) {
    return __builtin_bit_cast(unsigned short, (__bf16)f);
}
__device__ __forceinline__ float b2f(unsigned short b) {
    return __uint_as_float((unsigned)b << 16);
}
__device__ __forceinline__ unsigned pack2(float a, float b) {     // relu+pack
    bf16x2_t v = {(__bf16)fmaxf(a, 0.f), (__bf16)fmaxf(b, 0.f)};
    return __builtin_bit_cast(unsigned, v);
}
__device__ __forceinline__ unsigned pack2n(float a, float b) {    // pack only
    bf16x2_t v = {(__bf16)a, (__bf16)b};
    return __builtin_bit_cast(unsigned, v);
}

// combined conv1 weight values (derived R1, verified)
__device__ __forceinline__ float wcat_val(int k, int m, const float* relW, const float* rootW) {
    int part = k >> 7, c = k & 127, grp = m >> 5, mm = m & 31;
    int off = c * 32 + mm;
    if (part == 0) return (grp == 0) ? rootW[4096 + off] + rootW[8192 + off]
                        : (grp == 1) ? relW[off] : relW[3*4096 + off];
    if (part == 1) return (grp == 0) ? relW[1*4096 + off]
                        : (grp == 1) ? relW[6*4096 + off] : relW[5*4096 + off];
    return (grp == 0) ? relW[2*4096 + off]
         : (grp == 1) ? relW[4*4096 + off] : relW[7*4096 + off];
}
__device__ __forceinline__ float wc2_val(int k, int n, const float* relW, const float* rootW) {
    int grp = k >> 5, kk = k & 31;
    int off = kk * 128 + n;
    if (grp == 0) return rootW[4096 + off] + rootW[8192 + off];
    if (grp == 1) return relW[4096 + off];
    return relW[8192 + off];
}

// ---------------------------------------------------------------------------
// k_prep (R15): fragment tables for mfma_f32_32x32x16_bf16 in k_mlpE.
// 32x32x16 operand decode (inferred from the 16x16x32 pattern):
//   A/B: lane l holds m/n = l&31, k = (l>>5)*8 + j  (j = bf16 slot 0..7)
//   C/D: col = lane&31, row = (reg&3) + 8*(reg>>2) + 4*(lane>>5)  [verified]
// W0b:  [nt_h(8)][l][j] : W0 row j (j==INDIM -> b0, bias-in-MFMA), col 32nt+l31.
//       l>=32 (k=8..15) rows are zero.
// W1f:  [ks(17)][nt(4)][l][j] : h-dim permuted so the L2 B-operand equals the
//       packed L1 accumulator registers (same-lane):
//         virtual k=16ks+8hi+j  ->  hcol = 32*(ks>>1) + (r&3)+8*(r>>2)+4*hi,
//         r = (ks&1)*8 + j, hi = l>>5.
//       ks==16 is the b1 bias slice (only l<32,j==0 nonzero), consumed with a
//       constant ones-fragment.
// Mf:   [kt(8)][l][j] : e-dim permuted the same way (e from L2 acc registers):
//         ecol = 32*(kt>>1) + (r&3)+8*(r>>2)+4*hi, r=(kt&1)*8+j; tcol = l&31.
// k_tail tables (Wcatf/Wc2f/vW0f/vW1f, 16x16x32 layout) unchanged.
// ---------------------------------------------------------------------------
__global__ void k_prep(const float* __restrict__ c1_relW, const float* __restrict__ c1_relb,
                       const float* __restrict__ c1_rootW,
                       const float* __restrict__ c2_relW, const float* __restrict__ c2_relb,
                       const float* __restrict__ c2_rootW,
                       const float* __restrict__ wh_W0, const float* __restrict__ wh_W1,
                       const float* __restrict__ wo_W0, const float* __restrict__ wo_W1,
                       const float* __restrict__ wr_W0, const float* __restrict__ wr_W1,
                       const float* __restrict__ v_W0, const float* __restrict__ v_W1,
                       const float* __restrict__ b0h, const float* __restrict__ b0o,
                       const float* __restrict__ b0r,
                       const float* __restrict__ b1h, const float* __restrict__ b1o,
                       const float* __restrict__ b1r,
                       float* __restrict__ bcat, float* __restrict__ bc2,
                       unsigned short* __restrict__ W0b_h, unsigned short* __restrict__ W0b_o,
                       unsigned short* __restrict__ W0b_r,
                       unsigned short* __restrict__ W1f_h, unsigned short* __restrict__ W1f_o,
                       unsigned short* __restrict__ W1f_r,
                       unsigned short* __restrict__ Mf_h, unsigned short* __restrict__ Mf_o,
                       unsigned short* __restrict__ Wcatf, unsigned short* __restrict__ Wc2f,
                       unsigned short* __restrict__ vW0f, unsigned short* __restrict__ vW1f)
{
    int gid = blockIdx.x * blockDim.x + threadIdx.x;
    int gsz = gridDim.x * blockDim.x;

    for (int i = gid; i < 96; i += gsz) {
        int grp = i >> 5, mm = i & 31;
        float v;
        if (grp == 0)      v = c1_relb[32 + mm] + c1_relb[64 + mm];
        else if (grp == 1) v = c1_relb[mm] + c1_relb[128 + mm] + c1_relb[192 + mm];
        else               v = c1_relb[96 + mm] + c1_relb[160 + mm] + c1_relb[224 + mm];
        bcat[i] = v;
    }
    for (int i = gid; i < 128; i += gsz) bc2[i] = c2_relb[128 + i] + c2_relb[256 + i];

    // W0 fragments (32x32x16): 8 nt_h tiles x 64 lanes x 8 slots
    for (int i = gid; i < 4096; i += gsz) {
        int j = i & 7, l = (i >> 3) & 63, nh = i >> 9;
        int col = nh * 32 + (l & 31);
        unsigned short vh = 0, vo = 0, vr = 0;
        if (l < 32) {
            vh = (j < 7) ? f2b(wh_W0[j * 256 + col]) : f2b(b0h[col]);
            vo = (j < 7) ? f2b(wo_W0[j * 256 + col]) : f2b(b0o[col]);
            vr = (j < 6) ? f2b(wr_W0[j * 256 + col])
               : (j == 6) ? f2b(b0r[col]) : (unsigned short)0;
        }
        W0b_h[i] = vh; W0b_o[i] = vo; W0b_r[i] = vr;
    }
    // W1 fragments (32x32x16, permuted h-dim, 17th slice = b1)
    for (int i = gid; i < 34816; i += gsz) {
        int j = i & 7, l = (i >> 3) & 63, rem = i >> 9;
        int nt = rem & 3, ks = rem >> 2;
        int ecol = nt * 32 + (l & 31);
        int hh = l >> 5;
        unsigned short vh, vo, vr;
        if (ks < 16) {
            int r = (ks & 1) * 8 + j;
            int hcol = (ks >> 1) * 32 + (r & 3) + 8 * (r >> 2) + 4 * hh;
            vh = f2b(wh_W1[hcol * 128 + ecol]);
            vo = f2b(wo_W1[hcol * 128 + ecol]);
            vr = f2b(wr_W1[hcol * 128 + ecol]);
        } else {
            bool on = (l < 32) && (j == 0);
            vh = on ? f2b(b1h[ecol]) : (unsigned short)0;
            vo = on ? f2b(b1o[ecol]) : (unsigned short)0;
            vr = on ? f2b(b1r[ecol]) : (unsigned short)0;
        }
        W1f_h[i] = vh; W1f_o[i] = vo; W1f_r[i] = vr;
    }
    // Mf fragments (32x32x16, permuted e-dim)
    for (int i = gid; i < 4096; i += gsz) {
        int j = i & 7, l = (i >> 3) & 63, kt = i >> 9;
        int hh = l >> 5, s = kt & 1, r = s * 8 + j;
        int ecol = (kt >> 1) * 32 + (r & 3) + 8 * (r >> 2) + 4 * hh;
        int tcol = l & 31;
        int i0 = ecol * 32 + tcol;
        Mf_h[i] = f2b(c1_rootW[i0] + c1_rootW[4*4096 + i0] + c1_rootW[6*4096 + i0] - c1_relW[6*4096 + i0]);
        Mf_o[i] = f2b(c1_rootW[3*4096 + i0] + c1_rootW[5*4096 + i0] + c1_rootW[7*4096 + i0] - c1_relW[7*4096 + i0]);
    }
    // ---- k_tail tables (16x16x32 layout, unchanged) ----
    for (int i = gid; i < 36864; i += gsz) {
        int j = i & 7, l = (i >> 3) & 63, rem = i >> 9;
        int nt = rem % 6, ks = rem / 6;
        int k = ks * 32 + (l >> 4) * 8 + j;
        int n = nt * 16 + (l & 15);
        Wcatf[i] = f2b(wcat_val(k, n, c1_relW, c1_rootW));
    }
    for (int i = gid; i < 12288; i += gsz) {
        int j = i & 7, l = (i >> 3) & 63, rem = i >> 9;
        int nt = rem & 7, ks = rem >> 3;
        int k = ks * 32 + (l >> 4) * 8 + j;
        int n = nt * 16 + (l & 15);
        Wc2f[i] = f2b(wc2_val(k, n, c2_relW, c2_rootW));
    }
    for (int i = gid; i < 32768; i += gsz) {
        int j = i & 7, l = (i >> 3) & 63, rem = i >> 9;
        int nt = rem & 15, ks = rem >> 4;
        int k = ks * 32 + (l >> 4) * 8 + j;
        int n = nt * 16 + (l & 15);
        vW0f[i] = f2b(v_W0[k * 256 + n]);
    }
    for (int i = gid; i < 32768; i += gsz) {
        int j = i & 7, l = (i >> 3) & 63, rem = i >> 9;
        int nt = rem & 7, ks = rem >> 3;
        int k = ks * 32 + (l >> 4) * 8 + j;
        int n = nt * 16 + (l & 15);
        vW1f[i] = f2b(v_W1[k * 128 + n]);
    }
}

// ---------------------------------------------------------------------------
// mlp_blockE (R15): 32x32x16-MFMA dataflow. One 32-row sub replaces two
// 16-row subs -> W1 LDS fragments are read once per 32 rows (was per 16),
// L1 8 MFMAs (was 32/32rows), t 8 (was 16). Register-direct h->L2 and e->t
// (permuted tables; N-dim = lane&31 identical for producer and consumer).
// b1 enters as W1 K-slice 16 against a constant ones-fragment.
// Per-wave rows 64 -> 2 subs. ew scan keeps old [16][136] format via two
// 16-row half-passes (write half's lanes, scan, next half).
// LDS: W0s@0 8K | Mfs@8K 8K | W1s@16K 68K | ew@86016 16x4352 = 152K total.
// ---------------------------------------------------------------------------
#define SM_W0   0
#define SM_MF   8192
#define SM_W1   16384
#define SM_HS   86016
#define SM_SZ   (86016 + 16 * 16 * 136 * 2)

template<int NPB, int NODE0, int INOFF, int INDIM, bool TAIL>
__device__ __forceinline__ void mlp_blockE(
    int blkrow0, const float* __restrict__ state,
    const unsigned short* __restrict__ W0b_g,
    const unsigned short* __restrict__ W1f_g,
    const unsigned short* __restrict__ Mf_g,
    unsigned short* __restrict__ tR, float* __restrict__ sumB,
    unsigned short* __restrict__ eR, char* smem)
{
    unsigned short* W0s = (unsigned short*)(smem + SM_W0);
    unsigned short* Mfs = (unsigned short*)(smem + SM_MF);
    unsigned short* W1s = (unsigned short*)(smem + SM_W1);

    const int t = threadIdx.x;
    const int lane = t & 63;
    const int w = t >> 6;
    const int l31 = lane & 31;
    const int hi = lane >> 5;
    const int R0 = blkrow0 + w * 64;      // this wave's 64 contiguous rows
    unsigned short* ew = (unsigned short*)(smem + SM_HS) + w * (16 * 136); // [16][136]

    // ---- one-time staging (1024 threads) ----
    if (t < 512) ((uint4*)W0s)[t] = ((const uint4*)W0b_g)[t];
    if constexpr (TAIL) {
        if (t >= 512) ((uint4*)Mfs)[t - 512] = ((const uint4*)Mf_g)[t - 512];
    }
    #pragma unroll
    for (int i = 0; i < 4; ++i)
        ((uint4*)W1s)[t + 1024 * i] = ((const uint4*)W1f_g)[t + 1024 * i];
    if (t < 256) ((uint4*)W1s)[4096 + t] = ((const uint4*)W1f_g)[4096 + t];
    __syncthreads();   // the ONLY block-wide barrier

    // constant ones-fragment for the b1 bias K-slice (k-slot 0 on lo lanes)
    bf16x8 bones = {};
    if (lane < 32) bones[0] = (short)0x3F80;

    float s0 = 0.f, s1 = 0.f;
    int bcur = R0 / NPB;

    // ---- X pipeline: lanes 0..31 own rows l31; prefetch next sub ----
    float xf[INDIM];
    if (lane < 32) {
        int grow = R0 + l31;
        int b = grow / NPB;
        int n = grow - b * NPB + NODE0;
        const float* xp = state + ((size_t)b * NSTATE + n) * DIN + INOFF;
        #pragma unroll
        for (int j = 0; j < INDIM; ++j) xf[j] = xp[j];
    }

    for (int sub = 0; sub < 2; ++sub) {
        const int wrow0 = R0 + sub * 32;

        bf16x8 bx = {};
        if (lane < 32) {
            #pragma unroll
            for (int j = 0; j < INDIM; ++j) bx[j] = (short)f2b(xf[j]);
            bx[INDIM] = (short)0x3F80;   // multiplies the b0 A-slot
        }
        if (sub < 1 && lane < 32) {
            int grow = wrow0 + 32 + l31;
            int b = grow / NPB;
            int n = grow - b * NPB + NODE0;
            const float* xp = state + ((size_t)b * NSTATE + n) * DIN + INOFF;
            #pragma unroll
            for (int j = 0; j < INDIM; ++j) xf[j] = xp[j];
        }

        // ---- L1 + L2 interleaved: per h-tile nh, one 32x32 L1 MFMA makes
        // h cols 32nh..+31; pack regs 0..7 / 8..15 into the two K-slice
        // B-fragments and immediately burn them against 4 e-col tiles. ----
        f32x16 acc[4];
        #pragma unroll
        for (int nt = 0; nt < 4; ++nt) { f32x16 z = {}; acc[nt] = z; }
        #pragma unroll
        for (int nh = 0; nh < 8; ++nh) {
            bf16x8 aw0 = *(const bf16x8*)(W0s + (nh * 64 + lane) * 8);
            f32x16 z = {};
            f32x16 a1 = __builtin_amdgcn_mfma_f32_32x32x16_bf16(aw0, bx, z, 0, 0, 0);
            uint4 ua, ub;
            ua.x = pack2(a1[0], a1[1]);   ua.y = pack2(a1[2], a1[3]);
            ua.z = pack2(a1[4], a1[5]);   ua.w = pack2(a1[6], a1[7]);
            ub.x = pack2(a1[8], a1[9]);   ub.y = pack2(a1[10], a1[11]);
            ub.z = pack2(a1[12], a1[13]); ub.w = pack2(a1[14], a1[15]);
            bf16x8 bhA = __builtin_bit_cast(bf16x8, ua);
            bf16x8 bhB = __builtin_bit_cast(bf16x8, ub);
            #pragma unroll
            for (int nt = 0; nt < 4; ++nt) {
                bf16x8 aw = *(const bf16x8*)(W1s + (((2 * nh) * 4 + nt) * 64 + lane) * 8);
                acc[nt] = __builtin_amdgcn_mfma_f32_32x32x16_bf16(aw, bhA, acc[nt], 0, 0, 0);
            }
            #pragma unroll
            for (int nt = 0; nt < 4; ++nt) {
                bf16x8 aw = *(const bf16x8*)(W1s + (((2 * nh + 1) * 4 + nt) * 64 + lane) * 8);
                acc[nt] = __builtin_amdgcn_mfma_f32_32x32x16_bf16(aw, bhB, acc[nt], 0, 0, 0);
            }
        }
        // b1 bias K-slice
        #pragma unroll
        for (int nt = 0; nt < 4; ++nt) {
            bf16x8 aw = *(const bf16x8*)(W1s + ((64 + nt) * 64 + lane) * 8);
            acc[nt] = __builtin_amdgcn_mfma_f32_32x32x16_bf16(aw, bones, acc[nt], 0, 0, 0);
        }

        // relu+pack e once; feeds t-MFMA B, ew stores, eR stores
        unsigned pvu[4][8];
        #pragma unroll
        for (int nt = 0; nt < 4; ++nt)
            #pragma unroll
            for (int p = 0; p < 8; ++p)
                pvu[nt][p] = pack2(acc[nt][2 * p], acc[nt][2 * p + 1]);

        if constexpr (TAIL) {
            // t = e @ M : A=Mf (permuted e-dim), B=e from REGISTERS
            f32x16 tacc = {};
            #pragma unroll
            for (int kt = 0; kt < 8; ++kt) {
                const int nt = kt >> 1, s = kt & 1;
                uint4 ua = {pvu[nt][4 * s], pvu[nt][4 * s + 1],
                            pvu[nt][4 * s + 2], pvu[nt][4 * s + 3]};
                bf16x8 ae = __builtin_bit_cast(bf16x8, ua);
                bf16x8 bm = *(const bf16x8*)(Mfs + (kt * 64 + lane) * 8);
                tacc = __builtin_amdgcn_mfma_f32_32x32x16_bf16(bm, ae, tacc, 0, 0, 0);
            }
            // tR row-major store: lane's row = wrow0+l31; 16 t-cols per lane
            {
                unsigned short* tRrow = tR + (size_t)(wrow0 + l31) * 32 + 4 * hi;
                #pragma unroll
                for (int q = 0; q < 4; ++q) {
                    uint2 tv = {pack2n(tacc[4 * q], tacc[4 * q + 1]),
                                pack2n(tacc[4 * q + 2], tacc[4 * q + 3])};
                    *(uint2*)(tRrow + 8 * q) = tv;
                }
            }
            // ew + scan in two 16-row half-passes (preserves old scan format)
            #pragma unroll
            for (int half = 0; half < 2; ++half) {
                __asm__ __volatile__("s_waitcnt lgkmcnt(0)" ::: "memory");
                if ((l31 >> 4) == half) {
                    unsigned short* er = ew + (l31 & 15) * 136 + 4 * hi;
                    #pragma unroll
                    for (int nt = 0; nt < 4; ++nt)
                        #pragma unroll
                        for (int q = 0; q < 4; ++q)
                            *(uint2*)(er + nt * 32 + 8 * q) =
                                (uint2){pvu[nt][2 * q], pvu[nt][2 * q + 1]};
                }
                const int grow0 = wrow0 + half * 16;
                #pragma unroll
                for (int r = 0; r < 16; ++r) {
                    int b = (grow0 + r) / NPB;
                    if (b != bcur) {
                        bool interior = (bcur * NPB >= R0) && ((bcur + 1) * NPB <= R0 + 64);
                        float* dst = sumB + (size_t)bcur * 128 + 2 * lane;
                        if (interior) { dst[0] = s0; dst[1] = s1; }
                        else { atomicAdd(dst, s0); atomicAdd(dst + 1, s1); }
                        s0 = 0.f; s1 = 0.f; bcur = b;
                    }
                    unsigned v = *(const unsigned*)(ew + r * 136 + lane * 2);
                    s0 += b2f((unsigned short)v);
                    s1 += b2f((unsigned short)(v >> 16));
                }
            }
            if (sub == 1) {
                bool interior = (bcur * NPB >= R0) && ((bcur + 1) * NPB <= R0 + 64);
                float* dst = sumB + (size_t)bcur * 128 + 2 * lane;
                if (interior) { dst[0] = s0; dst[1] = s1; }
                else { atomicAdd(dst, s0); atomicAdd(dst + 1, s1); }
            }
        } else {
            // root: row-major global store eR[row][n]; lane row = wrow0+l31
            unsigned short* eRrow = eR + (size_t)(wrow0 + l31) * 128 + 4 * hi;
            #pragma unroll
            for (int nt = 0; nt < 4; ++nt)
                #pragma unroll
                for (int q = 0; q < 4; ++q)
                    *(uint2*)(eRrow + nt * 32 + 8 * q) =
                        (uint2){pvu[nt][2 * q], pvu[nt][2 * q + 1]};
        }
        __asm__ __volatile__("" ::: "memory");   // keep iteration LDS order
    }
}

__global__ __launch_bounds__(1024, 1) void k_mlpE(
    const float* __restrict__ state,
    const unsigned short* __restrict__ W0b_h,
    const unsigned short* __restrict__ W1f_h,
    const unsigned short* __restrict__ Mf_h, unsigned short* __restrict__ tR_h,
    float* __restrict__ shB,
    const unsigned short* __restrict__ W0b_o,
    const unsigned short* __restrict__ W1f_o,
    const unsigned short* __restrict__ Mf_o, unsigned short* __restrict__ tR_o,
    float* __restrict__ soB,
    const unsigned short* __restrict__ W0b_r,
    const unsigned short* __restrict__ W1f_r,
    unsigned short* __restrict__ eR)
{
    __shared__ __align__(16) char smem[SM_SZ];
    int bid = blockIdx.x;
    if (bid < 160)
        mlp_blockE<20, 0, 6, 7, true>(bid * 1024, state, W0b_h, W1f_h,
                                      Mf_h, tR_h, shB, nullptr, smem);
    else if (bid < 240)
        mlp_blockE<10, 20, 6, 7, true>((bid - 160) * 1024, state, W0b_o, W1f_o,
                                       Mf_o, tR_o, soB, nullptr, smem);
    else
        mlp_blockE<1, 0, 0, 6, false>((bid - 240) * 1024, state, W0b_r, W1f_r,
                                      nullptr, nullptr, nullptr, eR, smem);
}

// ---------------------------------------------------------------------------
// k_tail: FUSED u2 + sM + v, 16 b's per block, 512 blocks. UNCHANGED (R15):
// all consumed formats (eR, shB/soB, tR row-major) preserved.
// ---------------------------------------------------------------------------
__global__ __launch_bounds__(256, 2) void k_tail(
    const unsigned short* __restrict__ eR,
    const float* __restrict__ shB, const float* __restrict__ soB,
    const unsigned short* __restrict__ tR_h, const unsigned short* __restrict__ tR_o,
    const unsigned short* __restrict__ Wcatf, const float* __restrict__ bcat,
    const unsigned short* __restrict__ Wc2f, const float* __restrict__ bc2,
    const unsigned short* __restrict__ vW0f, const float* __restrict__ vb0,
    const unsigned short* __restrict__ vW1f, const float* __restrict__ vb1,
    const float* __restrict__ vW2, const float* __restrict__ vb2,
    float* __restrict__ out)
{
    __shared__ __align__(16) char sm[33024];
    unsigned short* Ub  = (unsigned short*)(sm);          // [16][400]
    unsigned short* V1b = (unsigned short*)(sm);          // alias  [16][264]
    unsigned short* Vb  = (unsigned short*)(sm + 12800);  // [16][104]
    float* chL          = (float*)(sm + 16128);           // [16][32]
    float* coL          = (float*)(sm + 18176);           // [16][32]
    unsigned short* Hb  = (unsigned short*)(sm + 20224);  // [16][136]
    float* V2b          = (float*)(sm + 24576);           // [16][132]

    const int t = threadIdx.x, lane = t & 63, w = t >> 6;
    const int l15 = lane & 15, quad = lane >> 4;
    const int b0 = blockIdx.x * 16;
    const int rowb = quad * 4;

    // ---- phase 1: stage U = [er | sh | so] ----
    {
        int b = t >> 4, q = t & 15;
        ((uint4*)(Ub + b * 400))[q] = ((const uint4*)(eR + (size_t)(b0 + b) * 128))[q];
    }
    for (int idx = t; idx < 4096; idx += 256) {
        int b = idx >> 8, kk = idx & 255;
        float v = (kk < 128) ? shB[(size_t)(b0 + b) * 128 + kk]
                             : soB[(size_t)(b0 + b) * 128 + kk - 128];
        Ub[b * 400 + 128 + kk] = f2b(v);
    }
    __syncthreads();

    // ---- phase 2: U-MFMA (unswapped, verified): xr / ch / co ----
    for (int nt = w; nt < 6; nt += 4) {
        float bias = bcat[nt * 16 + l15];
        f32x4 acc = {bias, bias, bias, bias};
        #pragma unroll
        for (int ks = 0; ks < 12; ++ks) {
            bf16x8 a = *(const bf16x8*)(Ub + l15 * 400 + ks * 32 + quad * 8);
            bf16x8 bw = *(const bf16x8*)(Wcatf + ((ks * 6 + nt) * 64 + lane) * 8);
            acc = __builtin_amdgcn_mfma_f32_16x16x32_bf16(a, bw, acc, 0, 0, 0);
        }
        int n = nt * 16 + l15;
        #pragma unroll
        for (int reg = 0; reg < 4; ++reg) {
            float v = acc[reg];
            int b = rowb + reg;
            if (n < 32)      Vb[b * 104 + n] = f2b(fmaxf(v, 0.f));
            else if (n < 64) chL[b * 32 + (n - 32)] = v;
            else             coL[b * 32 + (n - 64)] = v;
        }
    }
    __syncthreads();

    // ---- phase 3: t-scan (row-major tR, coalesced) -> s2h, s2o ----
    for (int idx = t; idx < 512; idx += 256) {
        int b = idx >> 5, m = idx & 31;
        float ch = chL[b * 32 + m];
        const unsigned short* p = tR_h + (size_t)(b0 + b) * 20 * 32 + m;
        float s = 0.f;
        #pragma unroll
        for (int n = 0; n < 20; ++n) s += fmaxf(ch + b2f(p[n * 32]), 0.f);
        Vb[b * 104 + 32 + m] = f2b(s);
        float co = coL[b * 32 + m];
        const unsigned short* p2 = tR_o + (size_t)(b0 + b) * 10 * 32 + m;
        float s2 = 0.f;
        #pragma unroll
        for (int n = 0; n < 10; ++n) s2 += fmaxf(co + b2f(p2[n * 32]), 0.f);
        Vb[b * 104 + 64 + m] = f2b(s2);
    }
    __syncthreads();

    // ---- phase 4: c2 (N=128, 2 nt per wave) ----
    {
        f32x4 acc[2];
        #pragma unroll
        for (int q = 0; q < 2; ++q) {
            int nt = w + q * 4;
            float bias = bc2[nt * 16 + l15];
            acc[q] = (f32x4){bias, bias, bias, bias};
        }
        #pragma unroll
        for (int ks = 0; ks < 3; ++ks) {
            bf16x8 a = *(const bf16x8*)(Vb + l15 * 104 + ks * 32 + quad * 8);
            #pragma unroll
            for (int q = 0; q < 2; ++q) {
                int nt = w + q * 4;
                bf16x8 bw = *(const bf16x8*)(Wc2f + ((ks * 8 + nt) * 64 + lane) * 8);
                acc[q] = __builtin_amdgcn_mfma_f32_16x16x32_bf16(a, bw, acc[q], 0, 0, 0);
            }
        }
        #pragma unroll
        for (int q = 0; q < 2; ++q) {
            int nt = w + q * 4;
            #pragma unroll
            for (int reg = 0; reg < 4; ++reg)
                Hb[(rowb + reg) * 136 + nt * 16 + l15] = f2b(fmaxf(acc[q][reg], 0.f));
        }
    }
    __syncthreads();

    // ---- phase 5: v1 (N=256, 4 nt per wave; V1b aliases dead Ub) ----
    {
        f32x4 acc[4];
        #pragma unroll
        for (int q = 0; q < 4; ++q) {
            int nt = w + q * 4;
            float bias = vb0[nt * 16 + l15];
            acc[q] = (f32x4){bias, bias, bias, bias};
        }
        #pragma unroll
        for (int ks = 0; ks < 4; ++ks) {
            bf16x8 a = *(const bf16x8*)(Hb + l15 * 136 + ks * 32 + quad * 8);
            #pragma unroll
            for (int q = 0; q < 4; ++q) {
                int nt = w + q * 4;
                bf16x8 bw = *(const bf16x8*)(vW0f + ((ks * 16 + nt) * 64 + lane) * 8);
                acc[q] = __builtin_amdgcn_mfma_f32_16x16x32_bf16(a, bw, acc[q], 0, 0, 0);
            }
        }
        __syncthreads();   // Ub reads (phase-2 done long ago) -> safe; order vs writes
        #pragma unroll
        for (int q = 0; q < 4; ++q) {
            int nt = w + q * 4;
            #pragma unroll
            for (int reg = 0; reg < 4; ++reg)
                V1b[(rowb + reg) * 264 + nt * 16 + l15] = f2b(fmaxf(acc[q][reg], 0.f));
        }
    }
    __syncthreads();

    // ---- phase 6: v2 (N=128, 2 nt per wave) ----
    {
        f32x4 acc[2];
        #pragma unroll
        for (int q = 0; q < 2; ++q) {
            int nt = w + q * 4;
            float bias = vb1[nt * 16 + l15];
            acc[q] = (f32x4){bias, bias, bias, bias};
        }
        #pragma unroll
        for (int ks = 0; ks < 8; ++ks) {
            bf16x8 a = *(const bf16x8*)(V1b + l15 * 264 + ks * 32 + quad * 8);
            #pragma unroll
            for (int q = 0; q < 2; ++q) {
                int nt = w + q * 4;
                bf16x8 bw = *(const bf16x8*)(vW1f + ((ks * 8 + nt) * 64 + lane) * 8);
                acc[q] = __builtin_amdgcn_mfma_f32_16x16x32_bf16(a, bw, acc[q], 0, 0, 0);
            }
        }
        #pragma unroll
        for (int q = 0; q < 2; ++q) {
            int nt = w + q * 4;
            #pragma unroll
            for (int reg = 0; reg < 4; ++reg)
                V2b[(rowb + reg) * 132 + nt * 16 + l15] = fmaxf(acc[q][reg], 0.f);
        }
    }
    __syncthreads();

    // ---- phase 7: v3, 8 threads per b + shuffle reduce ----
    if (t < 128) {
        int b = t >> 3, j = t & 7;
        float v = 0.f;
        #pragma unroll
        for (int k = 0; k < 16; ++k)
            v = fmaf(V2b[b * 132 + j * 16 + k], vW2[j * 16 + k], v);
        v += __shfl_down(v, 4, 8);
        v += __shfl_down(v, 2, 8);
        v += __shfl_down(v, 1, 8);
        if (j == 0) out[b0 + b] = v + vb2[0];
    }
}

// ---------------------------------------------------------------------------
extern "C" void kernel_launch(void* const* d_in, const int* in_sizes, int n_in,
                              void* d_out, int out_size, void* d_ws, size_t ws_size,
                              hipStream_t stream)
{
    const float* state   = (const float*)d_in[0];
    const float* wr_W0   = (const float*)d_in[2];
    const float* wr_b0   = (const float*)d_in[3];
    const float* wr_W1   = (const float*)d_in[4];
    const float* wr_b1   = (const float*)d_in[5];
    const float* wh_W0   = (const float*)d_in[6];
    const float* wh_b0   = (const float*)d_in[7];
    const float* wh_W1   = (const float*)d_in[8];
    const float* wh_b1   = (const float*)d_in[9];
    const float* wo_W0   = (const float*)d_in[10];
    const float* wo_b0   = (const float*)d_in[11];
    const float* wo_W1   = (const float*)d_in[12];
    const float* wo_b1   = (const float*)d_in[13];
    const float* c1_relW = (const float*)d_in[14];
    const float* c1_relb = (const float*)d_in[15];
    const float* c1_rootW= (const float*)d_in[16];
    const float* c2_relW = (const float*)d_in[17];
    const float* c2_relb = (const float*)d_in[18];
    const float* c2_rootW= (const float*)d_in[19];
    const float* v_W0    = (const float*)d_in[20];
    const float* v_b0    = (const float*)d_in[21];
    const float* v_W1    = (const float*)d_in[22];
    const float* v_b1    = (const float*)d_in[23];
    const float* v_W2    = (const float*)d_in[24];
    const float* v_b2    = (const float*)d_in[25];

    char* ws = (char*)d_ws;
    size_t off = 0;
    auto alloc = [&](size_t bytes) -> char* {
        char* p = ws + off;
        off = (off + bytes + 255) & ~(size_t)255;
        return p;
    };
    float* shB  = (float*)alloc((size_t)BATCH * 128 * 4);          // b-major sums
    float* soB  = (float*)alloc((size_t)BATCH * 128 * 4);          // contiguous with shB
    unsigned short* tR_h = (unsigned short*)alloc((size_t)163840 * 32 * 2);  // row-major
    unsigned short* tR_o = (unsigned short*)alloc((size_t)81920 * 32 * 2);   // row-major
    unsigned short* eR   = (unsigned short*)alloc((size_t)BATCH * 128 * 2);
    float* bcat = (float*)alloc(96 * 4);
    float* bc2  = (float*)alloc(128 * 4);
    unsigned short* W0b_h = (unsigned short*)alloc(4096 * 2);
    unsigned short* W0b_o = (unsigned short*)alloc(4096 * 2);
    unsigned short* W0b_r = (unsigned short*)alloc(4096 * 2);
    unsigned short* W1f_h = (unsigned short*)alloc(34816 * 2);
    unsigned short* W1f_o = (unsigned short*)alloc(34816 * 2);
    unsigned short* W1f_r = (unsigned short*)alloc(34816 * 2);
    unsigned short* Mf_h  = (unsigned short*)alloc(4096 * 2);
    unsigned short* Mf_o  = (unsigned short*)alloc(4096 * 2);
    unsigned short* Wcatf = (unsigned short*)alloc(36864 * 2);
    unsigned short* Wc2f  = (unsigned short*)alloc(12288 * 2);
    unsigned short* vW0f  = (unsigned short*)alloc(32768 * 2);
    unsigned short* vW1f  = (unsigned short*)alloc(32768 * 2);
    (void)ws_size; (void)in_sizes; (void)n_in; (void)out_size;

    hipMemsetAsync(shB, 0, (size_t)2 * BATCH * 128 * 4, stream);

    k_prep<<<256, 256, 0, stream>>>(c1_relW, c1_relb, c1_rootW, c2_relW, c2_relb, c2_rootW,
                                    wh_W0, wh_W1, wo_W0, wo_W1, wr_W0, wr_W1, v_W0, v_W1,
                                    wh_b0, wo_b0, wr_b0, wh_b1, wo_b1, wr_b1,
                                    bcat, bc2, W0b_h, W0b_o, W0b_r, W1f_h, W1f_o, W1f_r,
                                    Mf_h, Mf_o, Wcatf, Wc2f, vW0f, vW1f);

    k_mlpE<<<248, 1024, 0, stream>>>(state,
                                     W0b_h, W1f_h, Mf_h, tR_h, shB,
                                     W0b_o, W1f_o, Mf_o, tR_o, soB,
                                     W0b_r, W1f_r, eR);

    k_tail<<<512, 256, 0, stream>>>(eR, shB, soB, tR_h, tR_o,
                                    Wcatf, bcat, Wc2f, bc2, vW0f, v_b0, vW1f, v_b1,
                                    v_W2, v_b2, (float*)d_out);
}